// Round 1
// baseline (2674.684 us; speedup 1.0000x reference)
//
#include <hip/hip_runtime.h>
#include <hip/hip_bf16.h>
#include <cstddef>

// Problem constants
#define BB   16
#define LL   2048
#define DD   1024
#define SS   64
#define HH   512
#define H3   1536
#define NCLS 3

static __device__ __forceinline__ unsigned short f2bf(float f) {
    __hip_bfloat16 h = __float2bfloat16(f);
    return *reinterpret_cast<unsigned short*>(&h);
}
static __device__ __forceinline__ float bflo(unsigned int w) {
    return __uint_as_float(w << 16);
}
static __device__ __forceinline__ float bfhi(unsigned int w) {
    return __uint_as_float(w & 0xffff0000u);
}

// ---------------------------------------------------------------------------
// 1) Segment-mean pooling. One WG per (s,b) pair; output layout (S,B,D),
//    row r = s*16 + b  (the layout the GRU wants).
// ---------------------------------------------------------------------------
__global__ __launch_bounds__(256) void pool_kernel(
        const float* __restrict__ hs,      // (B, L, D)
        const int*   __restrict__ gidx,    // (B, L)
        float*       __restrict__ pooled)  // (S*B, D), row = s*16+b
{
    const int r = blockIdx.x;
    const int b = r & 15;
    const int s = r >> 4;
    __shared__ int lst[LL];
    __shared__ int cnt;
    const int tid = threadIdx.x;
    if (tid == 0) cnt = 0;
    __syncthreads();
    const int* gi = gidx + b * LL;
    for (int l = tid; l < LL; l += 256) {
        if (gi[l] == s) { int p = atomicAdd(&cnt, 1); lst[p] = l; }
    }
    __syncthreads();
    const int c = cnt;
    const float* hb = hs + (size_t)b * LL * DD;
    const int d0 = tid * 4;
    float4 acc = make_float4(0.f, 0.f, 0.f, 0.f);
    for (int i = 0; i < c; ++i) {
        const float4 v = *(const float4*)(hb + (size_t)lst[i] * DD + d0);
        acc.x += v.x; acc.y += v.y; acc.z += v.z; acc.w += v.w;
    }
    const float inv = 1.0f / (float)c;
    float4 o = make_float4(acc.x * inv, acc.y * inv, acc.z * inv, acc.w * inv);
    *(float4*)(pooled + (size_t)r * DD + d0) = o;
}

// ---------------------------------------------------------------------------
// 2) Transpose + bf16-pack W_hh (1536x512) -> Wp (256 x 1536) of uint32,
//    Wp[k2*1536 + g] packs bf16(W[g][2k2]) (lo) and bf16(W[g][2k2+1]) (hi).
// ---------------------------------------------------------------------------
__global__ __launch_bounds__(256) void pack_whh_kernel(
        const float* __restrict__ W,       // (1536, 512)
        unsigned int* __restrict__ Wp)     // (256, 1536)
{
    __shared__ float t[32][33];
    const int k0 = blockIdx.x * 32;        // 0..480
    const int g0 = blockIdx.y * 32;        // 0..1504
    const int tx = threadIdx.x;            // 0..31
    const int ty = threadIdx.y;            // 0..7
    for (int i = ty; i < 32; i += 8)
        t[i][tx] = W[(size_t)(g0 + i) * HH + k0 + tx];   // t[g_local][k_local]
    __syncthreads();
    for (int i = ty; i < 16; i += 8) {
        const float lo = t[tx][2 * i];
        const float hi = t[tx][2 * i + 1];
        const unsigned int p = (unsigned int)f2bf(lo) | ((unsigned int)f2bf(hi) << 16);
        Wp[(size_t)(k0 / 2 + i) * H3 + g0 + tx] = p;
    }
}

// ---------------------------------------------------------------------------
// 3) fp32 GEMM: C[M,N] = A[M,K] @ W[N,K]^T + bias[N] (+ resid[M,N]).
//    64x64 tile, BK=16, 256 threads, 4x4 per thread.
// ---------------------------------------------------------------------------
__global__ __launch_bounds__(256) void gemm_tn_kernel(
        const float* __restrict__ A,
        const float* __restrict__ W,
        const float* __restrict__ bias,
        const float* __restrict__ resid,   // nullable
        float*       __restrict__ C,
        int M, int N, int K)
{
    __shared__ float As[16][68];
    __shared__ float Bs[16][68];
    const int tid = threadIdx.x;
    const int tx = tid & 15, ty = tid >> 4;
    const int bx = blockIdx.x, by = blockIdx.y;
    const int lr  = tid >> 2;          // 0..63
    const int lc4 = (tid & 3) * 4;     // 0,4,8,12
    const float* Ab = A + (size_t)(by * 64 + lr) * K + lc4;
    const float* Wb = W + (size_t)(bx * 64 + lr) * K + lc4;
    float c[4][4] = {};
    for (int k0 = 0; k0 < K; k0 += 16) {
        const float4 av = *(const float4*)(Ab + k0);
        const float4 wv = *(const float4*)(Wb + k0);
        __syncthreads();
        As[lc4 + 0][lr] = av.x; As[lc4 + 1][lr] = av.y;
        As[lc4 + 2][lr] = av.z; As[lc4 + 3][lr] = av.w;
        Bs[lc4 + 0][lr] = wv.x; Bs[lc4 + 1][lr] = wv.y;
        Bs[lc4 + 2][lr] = wv.z; Bs[lc4 + 3][lr] = wv.w;
        __syncthreads();
#pragma unroll
        for (int k = 0; k < 16; ++k) {
            const float4 a  = *(const float4*)&As[k][ty * 4];
            const float4 bq = *(const float4*)&Bs[k][tx * 4];
            c[0][0] += a.x * bq.x; c[0][1] += a.x * bq.y; c[0][2] += a.x * bq.z; c[0][3] += a.x * bq.w;
            c[1][0] += a.y * bq.x; c[1][1] += a.y * bq.y; c[1][2] += a.y * bq.z; c[1][3] += a.y * bq.w;
            c[2][0] += a.z * bq.x; c[2][1] += a.z * bq.y; c[2][2] += a.z * bq.z; c[2][3] += a.z * bq.w;
            c[3][0] += a.w * bq.x; c[3][1] += a.w * bq.y; c[3][2] += a.w * bq.z; c[3][3] += a.w * bq.w;
        }
    }
    const int n0 = bx * 64 + tx * 4;
    const int m0 = by * 64 + ty * 4;
    const float4 bb = *(const float4*)(bias + n0);
#pragma unroll
    for (int i = 0; i < 4; ++i) {
        const size_t off = (size_t)(m0 + i) * N + n0;
        float4 o = make_float4(c[i][0] + bb.x, c[i][1] + bb.y,
                               c[i][2] + bb.z, c[i][3] + bb.w);
        if (resid) {
            const float4 rv = *(const float4*)(resid + off);
            o.x += rv.x; o.y += rv.y; o.z += rv.z; o.w += rv.w;
        }
        *(float4*)(C + off) = o;
    }
}

// ---------------------------------------------------------------------------
// 4) GRU recurrent layer. One WG per batch element b (16 WGs, 512 threads).
//    Thread j owns hidden dim j: computes hr[j], hz[j], hn[j] (512-dots
//    against LDS-resident h) then the full elementwise update for dim j.
//    W streamed from L2 as bf16 k-pair dwords.
// ---------------------------------------------------------------------------
__global__ __launch_bounds__(512) void gru_layer_kernel(
        const float*        __restrict__ xW,   // (S*B, 1536), row = t*16+b
        const unsigned int* __restrict__ Wp,   // (256, 1536) packed bf16 pairs
        const float*        __restrict__ b_hh, // (1536)
        float*              __restrict__ ys)   // (S*B, 512)
{
    const int b = blockIdx.x;
    const int j = threadIdx.x;                 // 0..511
    __shared__ float h[2][HH];
    h[0][j] = 0.f;
    const float bhr = b_hh[j];
    const float bhz = b_hh[HH + j];
    const float bhn = b_hh[2 * HH + j];
    __syncthreads();
    int cur = 0;
    for (int t = 0; t < SS; ++t) {
        float ar = bhr, az = bhz, an = bhn;
        const float* hc = h[cur];
#pragma unroll 4
        for (int k2 = 0; k2 < HH / 2; ++k2) {
            const float2 hk = *(const float2*)&hc[2 * k2];
            const unsigned int wr = Wp[k2 * H3 + j];
            const unsigned int wz = Wp[k2 * H3 + HH + j];
            const unsigned int wn = Wp[k2 * H3 + 2 * HH + j];
            ar += hk.x * bflo(wr) + hk.y * bfhi(wr);
            az += hk.x * bflo(wz) + hk.y * bfhi(wz);
            an += hk.x * bflo(wn) + hk.y * bfhi(wn);
        }
        const int row = t * BB + b;
        const float xr = xW[(size_t)row * H3 + j];
        const float xz = xW[(size_t)row * H3 + HH + j];
        const float xn = xW[(size_t)row * H3 + 2 * HH + j];
        const float rg = 1.f / (1.f + __expf(-(xr + ar)));
        const float zg = 1.f / (1.f + __expf(-(xz + az)));
        const float nn = xn + rg * an;
        const float e  = __expf(-2.f * nn);
        const float ng = (1.f - e) / (1.f + e);          // tanh
        const float hold = hc[j];
        const float hnew = (1.f - zg) * ng + zg * hold;
        h[cur ^ 1][j] = hnew;
        ys[(size_t)row * HH + j] = hnew;
        cur ^= 1;
        __syncthreads();
    }
}

// ---------------------------------------------------------------------------
// 5) Fused LayerNorm + classification head. One WG per output row.
//    Input layout (S,B,D) row s*16+b; output row r = b*64+s.
// ---------------------------------------------------------------------------
__global__ __launch_bounds__(256) void ln_head_kernel(
        const float* __restrict__ X,      // (S*B, D), row = s*16+b
        const float* __restrict__ gamma,
        const float* __restrict__ beta,
        const float* __restrict__ Wh,     // (3, 1024)
        const float* __restrict__ bh,     // (3)
        float*       __restrict__ out)    // (B*S, 3)
{
    __shared__ float red[12];
    const int r  = blockIdx.x;            // b*64 + s
    const int bI = r >> 6;
    const int s  = r & 63;
    const float* x = X + (size_t)(s * BB + bI) * DD;
    const int tid = threadIdx.x;
    const float4 v = *(const float4*)(x + tid * 4);
    float sum = v.x + v.y + v.z + v.w;
    float ss  = v.x * v.x + v.y * v.y + v.z * v.z + v.w * v.w;
#pragma unroll
    for (int o = 32; o > 0; o >>= 1) {
        sum += __shfl_down(sum, o, 64);
        ss  += __shfl_down(ss,  o, 64);
    }
    const int lane = tid & 63, w = tid >> 6;
    if (lane == 0) { red[w] = sum; red[4 + w] = ss; }
    __syncthreads();
    const float tsum = red[0] + red[1] + red[2] + red[3];
    const float tss  = red[4] + red[5] + red[6] + red[7];
    const float mu  = tsum * (1.f / (float)DD);
    const float var = tss * (1.f / (float)DD) - mu * mu;
    const float inv = rsqrtf(var + 1e-5f);
    const float4 g  = *(const float4*)(gamma + tid * 4);
    const float4 be = *(const float4*)(beta + tid * 4);
    float y0 = (v.x - mu) * inv * g.x + be.x;
    float y1 = (v.y - mu) * inv * g.y + be.y;
    float y2 = (v.z - mu) * inv * g.z + be.z;
    float y3 = (v.w - mu) * inv * g.w + be.w;
    const float4 w0 = *(const float4*)(Wh + 0 * DD + tid * 4);
    const float4 w1 = *(const float4*)(Wh + 1 * DD + tid * 4);
    const float4 w2 = *(const float4*)(Wh + 2 * DD + tid * 4);
    float p0 = y0 * w0.x + y1 * w0.y + y2 * w0.z + y3 * w0.w;
    float p1 = y0 * w1.x + y1 * w1.y + y2 * w1.z + y3 * w1.w;
    float p2 = y0 * w2.x + y1 * w2.y + y2 * w2.z + y3 * w2.w;
#pragma unroll
    for (int o = 32; o > 0; o >>= 1) {
        p0 += __shfl_down(p0, o, 64);
        p1 += __shfl_down(p1, o, 64);
        p2 += __shfl_down(p2, o, 64);
    }
    __syncthreads();   // red reuse
    if (lane == 0) { red[w] = p0; red[4 + w] = p1; red[8 + w] = p2; }
    __syncthreads();
    if (tid == 0) {
        out[(size_t)r * NCLS + 0] = red[0] + red[1] + red[2]  + red[3]  + bh[0];
        out[(size_t)r * NCLS + 1] = red[4] + red[5] + red[6]  + red[7]  + bh[1];
        out[(size_t)r * NCLS + 2] = red[8] + red[9] + red[10] + red[11] + bh[2];
    }
}

// ---------------------------------------------------------------------------
extern "C" void kernel_launch(void* const* d_in, const int* in_sizes, int n_in,
                              void* d_out, int out_size, void* d_ws, size_t ws_size,
                              hipStream_t stream) {
    const float* hs      = (const float*)d_in[0];
    const float* W_down  = (const float*)d_in[1];
    const float* b_down  = (const float*)d_in[2];
    const float* W_ih0   = (const float*)d_in[3];
    const float* W_hh0   = (const float*)d_in[4];
    const float* b_ih0   = (const float*)d_in[5];
    const float* b_hh0   = (const float*)d_in[6];
    const float* W_ih1   = (const float*)d_in[7];
    const float* W_hh1   = (const float*)d_in[8];
    const float* b_ih1   = (const float*)d_in[9];
    const float* b_hh1   = (const float*)d_in[10];
    const float* W_lin1  = (const float*)d_in[11];
    const float* b_lin1  = (const float*)d_in[12];
    const float* gamma   = (const float*)d_in[13];
    const float* beta    = (const float*)d_in[14];
    const float* W_head  = (const float*)d_in[15];
    const float* b_head  = (const float*)d_in[16];
    const int*   gidx    = (const int*)d_in[17];
    float* out = (float*)d_out;

    char* ws = (char*)d_ws;
    float* pooled = (float*)(ws);                         // 4 MB  (1024x1024)
    float* xd     = (float*)(ws + ((size_t)4  << 20));    // 2 MB  (1024x512)
    float* xW     = (float*)(ws + ((size_t)6  << 20));    // 6 MB  (1024x1536)
    float* ys0    = (float*)(ws + ((size_t)12 << 20));    // 2 MB
    float* ys1    = (float*)(ws + ((size_t)14 << 20));    // 2 MB
    float* xln    = (float*)(ws + ((size_t)16 << 20));    // 4 MB
    unsigned int* wp0 = (unsigned int*)(ws + ((size_t)20 << 20)); // 1.5 MB
    unsigned int* wp1 = (unsigned int*)(ws + ((size_t)22 << 20)); // 1.5 MB

    // 1) pooling (also the residual source), layout (S,B,D)
    pool_kernel<<<BB * SS, 256, 0, stream>>>(hs, gidx, pooled);

    // 2) pack recurrent weights (bf16 k-pairs, k-major)
    pack_whh_kernel<<<dim3(HH / 32, H3 / 32), dim3(32, 8), 0, stream>>>(W_hh0, wp0);
    pack_whh_kernel<<<dim3(HH / 32, H3 / 32), dim3(32, 8), 0, stream>>>(W_hh1, wp1);

    // 3) down-projection: xd = pooled @ W_down^T + b_down   (1024x1024x512)
    gemm_tn_kernel<<<dim3(HH / 64, (SS * BB) / 64), 256, 0, stream>>>(
        pooled, W_down, b_down, nullptr, xd, SS * BB, HH, DD);

    // 4) layer-0 input projection: xW = xd @ W_ih0^T + b_ih0
    gemm_tn_kernel<<<dim3(H3 / 64, (SS * BB) / 64), 256, 0, stream>>>(
        xd, W_ih0, b_ih0, nullptr, xW, SS * BB, H3, HH);

    // 5) layer-0 recurrence
    gru_layer_kernel<<<BB, HH, 0, stream>>>(xW, wp0, b_hh0, ys0);

    // 6) layer-1 input projection
    gemm_tn_kernel<<<dim3(H3 / 64, (SS * BB) / 64), 256, 0, stream>>>(
        ys0, W_ih1, b_ih1, nullptr, xW, SS * BB, H3, HH);

    // 7) layer-1 recurrence
    gru_layer_kernel<<<BB, HH, 0, stream>>>(xW, wp1, b_hh1, ys1);

    // 8) up-projection + residual: xln = pooled + ys1 @ W_lin1^T + b_lin1
    gemm_tn_kernel<<<dim3(DD / 64, (SS * BB) / 64), 256, 0, stream>>>(
        ys1, W_lin1, b_lin1, pooled, xln, SS * BB, DD, HH);

    // 9) LayerNorm + head
    ln_head_kernel<<<BB * SS, 256, 0, stream>>>(xln, gamma, beta, W_head, b_head, out);
}

// Round 2
// 2185.376 us; speedup vs baseline: 1.2239x; 1.2239x over previous
//
#include <hip/hip_runtime.h>
#include <hip/hip_bf16.h>
#include <cstddef>

// Problem constants
#define BB   16
#define LL   2048
#define DD   1024
#define SS   64
#define HH   512
#define H3   1536
#define NCLS 3
#define GPB  16   // WGs per batch in the GRU (each owns 32 of 512 hidden dims)

static __device__ __forceinline__ unsigned short f2bf(float f) {
    __hip_bfloat16 h = __float2bfloat16(f);
    return *reinterpret_cast<unsigned short*>(&h);
}
static __device__ __forceinline__ float bflo(unsigned int w) {
    return __uint_as_float(w << 16);
}
static __device__ __forceinline__ float bfhi(unsigned int w) {
    return __uint_as_float(w & 0xffff0000u);
}

// ---------------------------------------------------------------------------
// 1) Segment-mean pooling. One WG per (s,b) pair; output layout (S,B,D),
//    row r = s*16 + b  (the layout the GRU wants).
// ---------------------------------------------------------------------------
__global__ __launch_bounds__(256) void pool_kernel(
        const float* __restrict__ hs,      // (B, L, D)
        const int*   __restrict__ gidx,    // (B, L)
        float*       __restrict__ pooled)  // (S*B, D), row = s*16+b
{
    const int r = blockIdx.x;
    const int b = r & 15;
    const int s = r >> 4;
    __shared__ int lst[LL];
    __shared__ int cnt;
    const int tid = threadIdx.x;
    if (tid == 0) cnt = 0;
    __syncthreads();
    const int* gi = gidx + b * LL;
    for (int l = tid; l < LL; l += 256) {
        if (gi[l] == s) { int p = atomicAdd(&cnt, 1); lst[p] = l; }
    }
    __syncthreads();
    const int c = cnt;
    const float* hb = hs + (size_t)b * LL * DD;
    const int d0 = tid * 4;
    float4 acc = make_float4(0.f, 0.f, 0.f, 0.f);
    for (int i = 0; i < c; ++i) {
        const float4 v = *(const float4*)(hb + (size_t)lst[i] * DD + d0);
        acc.x += v.x; acc.y += v.y; acc.z += v.z; acc.w += v.w;
    }
    const float inv = 1.0f / (float)c;
    float4 o = make_float4(acc.x * inv, acc.y * inv, acc.z * inv, acc.w * inv);
    *(float4*)(pooled + (size_t)r * DD + d0) = o;
}

// ---------------------------------------------------------------------------
// 2) Transpose + bf16-pack W_hh (1536x512) -> Wp (256 x 1536) of uint32,
//    Wp[k2*1536 + g] packs bf16(W[g][2k2]) (lo) and bf16(W[g][2k2+1]) (hi).
//    k-major so a wave's 64 lanes (consecutive g) read coalesced dwords.
// ---------------------------------------------------------------------------
__global__ __launch_bounds__(256) void pack_whh_kernel(
        const float* __restrict__ W,       // (1536, 512)
        unsigned int* __restrict__ Wp)     // (256, 1536)
{
    __shared__ float t[32][33];
    const int k0 = blockIdx.x * 32;        // 0..480
    const int g0 = blockIdx.y * 32;        // 0..1504
    const int tx = threadIdx.x;            // 0..31
    const int ty = threadIdx.y;            // 0..7
    for (int i = ty; i < 32; i += 8)
        t[i][tx] = W[(size_t)(g0 + i) * HH + k0 + tx];   // t[g_local][k_local]
    __syncthreads();
    for (int i = ty; i < 16; i += 8) {
        const float lo = t[tx][2 * i];
        const float hi = t[tx][2 * i + 1];
        const unsigned int p = (unsigned int)f2bf(lo) | ((unsigned int)f2bf(hi) << 16);
        Wp[(size_t)(k0 / 2 + i) * H3 + g0 + tx] = p;
    }
}

// ---------------------------------------------------------------------------
// 3) fp32 GEMM: C[M,N] = A[M,K] @ W[N,K]^T + bias[N] (+ resid[M,N]).
//    64x64 tile, BK=16, 256 threads, 4x4 per thread.
// ---------------------------------------------------------------------------
__global__ __launch_bounds__(256) void gemm_tn_kernel(
        const float* __restrict__ A,
        const float* __restrict__ W,
        const float* __restrict__ bias,
        const float* __restrict__ resid,   // nullable
        float*       __restrict__ C,
        int M, int N, int K)
{
    __shared__ float As[16][68];
    __shared__ float Bs[16][68];
    const int tid = threadIdx.x;
    const int tx = tid & 15, ty = tid >> 4;
    const int bx = blockIdx.x, by = blockIdx.y;
    const int lr  = tid >> 2;          // 0..63
    const int lc4 = (tid & 3) * 4;     // 0,4,8,12
    const float* Ab = A + (size_t)(by * 64 + lr) * K + lc4;
    const float* Wb = W + (size_t)(bx * 64 + lr) * K + lc4;
    float c[4][4] = {};
    for (int k0 = 0; k0 < K; k0 += 16) {
        const float4 av = *(const float4*)(Ab + k0);
        const float4 wv = *(const float4*)(Wb + k0);
        __syncthreads();
        As[lc4 + 0][lr] = av.x; As[lc4 + 1][lr] = av.y;
        As[lc4 + 2][lr] = av.z; As[lc4 + 3][lr] = av.w;
        Bs[lc4 + 0][lr] = wv.x; Bs[lc4 + 1][lr] = wv.y;
        Bs[lc4 + 2][lr] = wv.z; Bs[lc4 + 3][lr] = wv.w;
        __syncthreads();
#pragma unroll
        for (int k = 0; k < 16; ++k) {
            const float4 a  = *(const float4*)&As[k][ty * 4];
            const float4 bq = *(const float4*)&Bs[k][tx * 4];
            c[0][0] += a.x * bq.x; c[0][1] += a.x * bq.y; c[0][2] += a.x * bq.z; c[0][3] += a.x * bq.w;
            c[1][0] += a.y * bq.x; c[1][1] += a.y * bq.y; c[1][2] += a.y * bq.z; c[1][3] += a.y * bq.w;
            c[2][0] += a.z * bq.x; c[2][1] += a.z * bq.y; c[2][2] += a.z * bq.z; c[2][3] += a.z * bq.w;
            c[3][0] += a.w * bq.x; c[3][1] += a.w * bq.y; c[3][2] += a.w * bq.z; c[3][3] += a.w * bq.w;
        }
    }
    const int n0 = bx * 64 + tx * 4;
    const int m0 = by * 64 + ty * 4;
    const float4 bb = *(const float4*)(bias + n0);
#pragma unroll
    for (int i = 0; i < 4; ++i) {
        const size_t off = (size_t)(m0 + i) * N + n0;
        float4 o = make_float4(c[i][0] + bb.x, c[i][1] + bb.y,
                               c[i][2] + bb.z, c[i][3] + bb.w);
        if (resid) {
            const float4 rv = *(const float4*)(resid + off);
            o.x += rv.x; o.y += rv.y; o.z += rv.z; o.w += rv.w;
        }
        *(float4*)(C + off) = o;
    }
}

// ---------------------------------------------------------------------------
// 4) GRU recurrent layer, v2: 256 WGs (16 per batch). WG (b,p) owns hidden
//    dims j in [32p, 32p+32) -> 96 weight rows (r,z,n), streamed from L2
//    each step (k-major coalesced). h exchanged through a double-buffered
//    global buffer with a per-batch arrival counter (agent-scope atomics).
//
//    Ordering argument: h stores are RELEASE-agent; __syncthreads drains
//    vmcnt(0) so all 32 stores have reached the coherence point before the
//    leader's RELEASE fetch_add. Readers ACQUIRE-spin on the counter, then
//    RELAXED-agent load h (L1-bypassing). Double buffer (read (t-1)&1,
//    write t&1) makes one sync per step race-free: cnt>=16*t implies every
//    WG finished *reading* h_{t-2}, whose buffer step t overwrites.
// ---------------------------------------------------------------------------
__global__ __launch_bounds__(256) void gru_layer2_kernel(
        const float*        __restrict__ xW,   // (S*B, 1536), row = t*16+b
        const unsigned int* __restrict__ Wp,   // (256, 1536) packed bf16 pairs
        const float*        __restrict__ b_hh, // (1536)
        float*              __restrict__ ys,   // (S*B, 512)
        float*              __restrict__ hg,   // (B, 2, 512) h exchange
        int*                __restrict__ cnt)  // (B) arrival counters (pre-zeroed)
{
    const int wg = blockIdx.x;
    const int b  = wg & 15;
    const int p  = wg >> 4;                    // 0..15
    const int tid = threadIdx.x;               // 0..255 (threads >=192 idle in dot)

    __shared__ float hs[HH];                   // h_{t-1} staged (fp32)
    __shared__ float dots[96];                 // hW pre-activations for this WG

    // dot-thread assignment: tid = 2*r + half, r = gate*32 + jl
    const int r    = tid >> 1;                 // 0..95 (valid when tid<192)
    const int half = tid & 1;                  // k-half: [0,256) or [256,512)
    const int gate = r >> 5;
    const int jl   = r & 31;
    const int col  = gate * HH + p * 32 + jl;  // column in Wp / row in W_hh
    const float bias = (tid < 192) ? b_hh[col] : 0.f;
    const unsigned int* wbase = Wp + (size_t)(half * 128) * H3 + col;

    for (int t = 0; t < SS; ++t) {
        // ---- wait for h_{t-1}, stage into LDS ----
        if (t > 0) {
            if (tid == 0) {
                while (__hip_atomic_load(cnt + b, __ATOMIC_ACQUIRE,
                                         __HIP_MEMORY_SCOPE_AGENT) < GPB * t)
                    __builtin_amdgcn_s_sleep(1);
            }
            __syncthreads();
            const float* src = hg + ((size_t)b * 2 + ((t - 1) & 1)) * HH;
            hs[tid]       = __hip_atomic_load(src + tid, __ATOMIC_RELAXED,
                                              __HIP_MEMORY_SCOPE_AGENT);
            hs[256 + tid] = __hip_atomic_load(src + 256 + tid, __ATOMIC_RELAXED,
                                              __HIP_MEMORY_SCOPE_AGENT);
        } else {
            hs[tid] = 0.f;
            hs[256 + tid] = 0.f;
        }
        __syncthreads();

        // ---- 96 dots of length 512 (each thread: one row-half of 256 k) ----
        if (tid < 192) {
            float acc = 0.f;
            const unsigned int* wp = wbase;
            const float* hp = hs + half * 256;
#pragma unroll 8
            for (int i = 0; i < 128; ++i) {
                const unsigned int w = *wp; wp += H3;
                const float2 h2 = *(const float2*)hp; hp += 2;
                acc += h2.x * bflo(w);
                acc += h2.y * bfhi(w);
            }
            acc += __shfl_xor(acc, 1, 64);     // combine the two k-halves
            if (half == 0) dots[r] = acc + bias;
        }
        __syncthreads();

        // ---- gate math + h update for this WG's 32 dims ----
        if (tid < 32) {
            const int j   = p * 32 + tid;
            const int row = t * BB + b;
            const float xr = xW[(size_t)row * H3 + j];
            const float xz = xW[(size_t)row * H3 + HH + j];
            const float xn = xW[(size_t)row * H3 + 2 * HH + j];
            const float ar = dots[tid];
            const float az = dots[32 + tid];
            const float an = dots[64 + tid];
            const float rg = 1.f / (1.f + __expf(-(xr + ar)));
            const float zg = 1.f / (1.f + __expf(-(xz + az)));
            const float nn = xn + rg * an;
            const float e  = __expf(-2.f * nn);
            const float ng = (1.f - e) / (1.f + e);          // tanh
            const float hold = hs[j];
            const float hnew = (1.f - zg) * ng + zg * hold;
            ys[(size_t)row * HH + j] = hnew;                 // consumed next kernel
            __hip_atomic_store(hg + ((size_t)b * 2 + (t & 1)) * HH + j, hnew,
                               __ATOMIC_RELEASE, __HIP_MEMORY_SCOPE_AGENT);
        }
        __syncthreads();   // drains vmcnt(0): stores at coherence point
        if (tid == 0)
            __hip_atomic_fetch_add(cnt + b, 1, __ATOMIC_RELEASE,
                                   __HIP_MEMORY_SCOPE_AGENT);
    }
}

// ---------------------------------------------------------------------------
// 5) Fused LayerNorm + classification head. One WG per output row.
//    Input layout (S,B,D) row s*16+b; output row r = b*64+s.
// ---------------------------------------------------------------------------
__global__ __launch_bounds__(256) void ln_head_kernel(
        const float* __restrict__ X,      // (S*B, D), row = s*16+b
        const float* __restrict__ gamma,
        const float* __restrict__ beta,
        const float* __restrict__ Wh,     // (3, 1024)
        const float* __restrict__ bh,     // (3)
        float*       __restrict__ out)    // (B*S, 3)
{
    __shared__ float red[12];
    const int r  = blockIdx.x;            // b*64 + s
    const int bI = r >> 6;
    const int s  = r & 63;
    const float* x = X + (size_t)(s * BB + bI) * DD;
    const int tid = threadIdx.x;
    const float4 v = *(const float4*)(x + tid * 4);
    float sum = v.x + v.y + v.z + v.w;
    float ss  = v.x * v.x + v.y * v.y + v.z * v.z + v.w * v.w;
#pragma unroll
    for (int o = 32; o > 0; o >>= 1) {
        sum += __shfl_down(sum, o, 64);
        ss  += __shfl_down(ss,  o, 64);
    }
    const int lane = tid & 63, w = tid >> 6;
    if (lane == 0) { red[w] = sum; red[4 + w] = ss; }
    __syncthreads();
    const float tsum = red[0] + red[1] + red[2] + red[3];
    const float tss  = red[4] + red[5] + red[6] + red[7];
    const float mu  = tsum * (1.f / (float)DD);
    const float var = tss * (1.f / (float)DD) - mu * mu;
    const float inv = rsqrtf(var + 1e-5f);
    const float4 g  = *(const float4*)(gamma + tid * 4);
    const float4 be = *(const float4*)(beta + tid * 4);
    float y0 = (v.x - mu) * inv * g.x + be.x;
    float y1 = (v.y - mu) * inv * g.y + be.y;
    float y2 = (v.z - mu) * inv * g.z + be.z;
    float y3 = (v.w - mu) * inv * g.w + be.w;
    const float4 w0 = *(const float4*)(Wh + 0 * DD + tid * 4);
    const float4 w1 = *(const float4*)(Wh + 1 * DD + tid * 4);
    const float4 w2 = *(const float4*)(Wh + 2 * DD + tid * 4);
    float p0 = y0 * w0.x + y1 * w0.y + y2 * w0.z + y3 * w0.w;
    float p1 = y0 * w1.x + y1 * w1.y + y2 * w1.z + y3 * w1.w;
    float p2 = y0 * w2.x + y1 * w2.y + y2 * w2.z + y3 * w2.w;
#pragma unroll
    for (int o = 32; o > 0; o >>= 1) {
        p0 += __shfl_down(p0, o, 64);
        p1 += __shfl_down(p1, o, 64);
        p2 += __shfl_down(p2, o, 64);
    }
    __syncthreads();   // red reuse
    if (lane == 0) { red[w] = p0; red[4 + w] = p1; red[8 + w] = p2; }
    __syncthreads();
    if (tid == 0) {
        out[(size_t)r * NCLS + 0] = red[0] + red[1] + red[2]  + red[3]  + bh[0];
        out[(size_t)r * NCLS + 1] = red[4] + red[5] + red[6]  + red[7]  + bh[1];
        out[(size_t)r * NCLS + 2] = red[8] + red[9] + red[10] + red[11] + bh[2];
    }
}

// ---------------------------------------------------------------------------
extern "C" void kernel_launch(void* const* d_in, const int* in_sizes, int n_in,
                              void* d_out, int out_size, void* d_ws, size_t ws_size,
                              hipStream_t stream) {
    const float* hs      = (const float*)d_in[0];
    const float* W_down  = (const float*)d_in[1];
    const float* b_down  = (const float*)d_in[2];
    const float* W_ih0   = (const float*)d_in[3];
    const float* W_hh0   = (const float*)d_in[4];
    const float* b_ih0   = (const float*)d_in[5];
    const float* b_hh0   = (const float*)d_in[6];
    const float* W_ih1   = (const float*)d_in[7];
    const float* W_hh1   = (const float*)d_in[8];
    const float* b_ih1   = (const float*)d_in[9];
    const float* b_hh1   = (const float*)d_in[10];
    const float* W_lin1  = (const float*)d_in[11];
    const float* b_lin1  = (const float*)d_in[12];
    const float* gamma   = (const float*)d_in[13];
    const float* beta    = (const float*)d_in[14];
    const float* W_head  = (const float*)d_in[15];
    const float* b_head  = (const float*)d_in[16];
    const int*   gidx    = (const int*)d_in[17];
    float* out = (float*)d_out;

    char* ws = (char*)d_ws;
    float* pooled = (float*)(ws);                         // 4 MB  (1024x1024)
    float* xd     = (float*)(ws + ((size_t)4  << 20));    // 2 MB  (1024x512)
    float* xW     = (float*)(ws + ((size_t)6  << 20));    // 6 MB  (1024x1536)
    float* ys0    = (float*)(ws + ((size_t)12 << 20));    // 2 MB
    float* ys1    = (float*)(ws + ((size_t)14 << 20));    // 2 MB
    float* xln    = (float*)(ws + ((size_t)16 << 20));    // 4 MB
    unsigned int* wp0 = (unsigned int*)(ws + ((size_t)20 << 20)); // 1.5 MB
    unsigned int* wp1 = (unsigned int*)(ws + ((size_t)22 << 20)); // 1.5 MB
    float* hg  = (float*)(ws + ((size_t)23 << 20) + (512 << 10)); // 64 KB (B,2,512)
    int*   cnt = (int*)  (ws + ((size_t)23 << 20) + (640 << 10)); // 2*16 ints

    // zero the arrival counters (ws is poisoned before every launch)
    hipMemsetAsync(cnt, 0, 2 * BB * sizeof(int), stream);

    // 1) pooling (also the residual source), layout (S,B,D)
    pool_kernel<<<BB * SS, 256, 0, stream>>>(hs, gidx, pooled);

    // 2) pack recurrent weights (bf16 k-pairs, k-major)
    pack_whh_kernel<<<dim3(HH / 32, H3 / 32), dim3(32, 8), 0, stream>>>(W_hh0, wp0);
    pack_whh_kernel<<<dim3(HH / 32, H3 / 32), dim3(32, 8), 0, stream>>>(W_hh1, wp1);

    // 3) down-projection: xd = pooled @ W_down^T + b_down   (1024x1024x512)
    gemm_tn_kernel<<<dim3(HH / 64, (SS * BB) / 64), 256, 0, stream>>>(
        pooled, W_down, b_down, nullptr, xd, SS * BB, HH, DD);

    // 4) layer-0 input projection: xW = xd @ W_ih0^T + b_ih0
    gemm_tn_kernel<<<dim3(H3 / 64, (SS * BB) / 64), 256, 0, stream>>>(
        xd, W_ih0, b_ih0, nullptr, xW, SS * BB, H3, HH);

    // 5) layer-0 recurrence (256 WGs, 16 per batch)
    gru_layer2_kernel<<<BB * GPB, 256, 0, stream>>>(xW, wp0, b_hh0, ys0, hg, cnt);

    // 6) layer-1 input projection
    gemm_tn_kernel<<<dim3(H3 / 64, (SS * BB) / 64), 256, 0, stream>>>(
        ys0, W_ih1, b_ih1, nullptr, xW, SS * BB, H3, HH);

    // 7) layer-1 recurrence
    gru_layer2_kernel<<<BB * GPB, 256, 0, stream>>>(xW, wp1, b_hh1, ys1, hg, cnt + BB);

    // 8) up-projection + residual: xln = pooled + ys1 @ W_lin1^T + b_lin1
    gemm_tn_kernel<<<dim3(DD / 64, (SS * BB) / 64), 256, 0, stream>>>(
        ys1, W_lin1, b_lin1, pooled, xln, SS * BB, DD, HH);

    // 9) LayerNorm + head
    ln_head_kernel<<<BB * SS, 256, 0, stream>>>(xln, gamma, beta, W_head, b_head, out);
}

// Round 3
// 1401.380 us; speedup vs baseline: 1.9086x; 1.5594x over previous
//
#include <hip/hip_runtime.h>
#include <hip/hip_bf16.h>
#include <cstddef>

// Problem constants
#define BB   16
#define LL   2048
#define DD   1024
#define SS   64
#define HH   512
#define H3   1536
#define NCLS 3
#define GPB  16   // WGs per batch in the GRU (each owns 32 of 512 hidden dims)

typedef _Float16 half2_t __attribute__((ext_vector_type(2)));

static __device__ __forceinline__ half2_t u2h2(unsigned int u) {
    union { unsigned int u; half2_t h; } cv; cv.u = u; return cv.h;
}
static __device__ __forceinline__ unsigned short f2h(float f) {
    _Float16 h = (_Float16)f;
    union { _Float16 h; unsigned short u; } cv; cv.h = h; return cv.u;
}

// ---------------------------------------------------------------------------
// 1) Segment-mean pooling. One WG per (s,b) pair; output layout (S,B,D),
//    row r = s*16 + b  (the layout the GRU wants).
// ---------------------------------------------------------------------------
__global__ __launch_bounds__(256) void pool_kernel(
        const float* __restrict__ hs,      // (B, L, D)
        const int*   __restrict__ gidx,    // (B, L)
        float*       __restrict__ pooled)  // (S*B, D), row = s*16+b
{
    const int r = blockIdx.x;
    const int b = r & 15;
    const int s = r >> 4;
    __shared__ int lst[LL];
    __shared__ int cnt;
    const int tid = threadIdx.x;
    if (tid == 0) cnt = 0;
    __syncthreads();
    const int* gi = gidx + b * LL;
    for (int l = tid; l < LL; l += 256) {
        if (gi[l] == s) { int p = atomicAdd(&cnt, 1); lst[p] = l; }
    }
    __syncthreads();
    const int c = cnt;
    const float* hb = hs + (size_t)b * LL * DD;
    const int d0 = tid * 4;
    float4 acc = make_float4(0.f, 0.f, 0.f, 0.f);
    for (int i = 0; i < c; ++i) {
        const float4 v = *(const float4*)(hb + (size_t)lst[i] * DD + d0);
        acc.x += v.x; acc.y += v.y; acc.z += v.z; acc.w += v.w;
    }
    const float inv = 1.0f / (float)c;
    float4 o = make_float4(acc.x * inv, acc.y * inv, acc.z * inv, acc.w * inv);
    *(float4*)(pooled + (size_t)r * DD + d0) = o;
}

// ---------------------------------------------------------------------------
// 2) Transpose + f16-pack W_hh (1536x512) -> Wp (256 x 1536) of uint32,
//    Wp[k2*1536 + g] packs f16(W[g][2k2]) (lo) and f16(W[g][2k2+1]) (hi).
//    k-major so consecutive g are coalesced dwords.
// ---------------------------------------------------------------------------
__global__ __launch_bounds__(256) void pack_whh_kernel(
        const float* __restrict__ W,       // (1536, 512)
        unsigned int* __restrict__ Wp)     // (256, 1536)
{
    __shared__ float t[32][33];
    const int k0 = blockIdx.x * 32;        // 0..480
    const int g0 = blockIdx.y * 32;        // 0..1504
    const int tx = threadIdx.x;            // 0..31
    const int ty = threadIdx.y;            // 0..7
    for (int i = ty; i < 32; i += 8)
        t[i][tx] = W[(size_t)(g0 + i) * HH + k0 + tx];   // t[g_local][k_local]
    __syncthreads();
    for (int i = ty; i < 16; i += 8) {
        const float lo = t[tx][2 * i];
        const float hi = t[tx][2 * i + 1];
        const unsigned int p = (unsigned int)f2h(lo) | ((unsigned int)f2h(hi) << 16);
        Wp[(size_t)(k0 / 2 + i) * H3 + g0 + tx] = p;
    }
}

// ---------------------------------------------------------------------------
// 3) fp32 GEMM: C[M,N] = A[M,K] @ W[N,K]^T + bias[N] (+ resid[M,N]).
//    64x64 tile, BK=16, 256 threads, 4x4 per thread.
// ---------------------------------------------------------------------------
__global__ __launch_bounds__(256) void gemm_tn_kernel(
        const float* __restrict__ A,
        const float* __restrict__ W,
        const float* __restrict__ bias,
        const float* __restrict__ resid,   // nullable
        float*       __restrict__ C,
        int M, int N, int K)
{
    __shared__ float As[16][68];
    __shared__ float Bs[16][68];
    const int tid = threadIdx.x;
    const int tx = tid & 15, ty = tid >> 4;
    const int bx = blockIdx.x, by = blockIdx.y;
    const int lr  = tid >> 2;          // 0..63
    const int lc4 = (tid & 3) * 4;     // 0,4,8,12
    const float* Ab = A + (size_t)(by * 64 + lr) * K + lc4;
    const float* Wb = W + (size_t)(bx * 64 + lr) * K + lc4;
    float c[4][4] = {};
    for (int k0 = 0; k0 < K; k0 += 16) {
        const float4 av = *(const float4*)(Ab + k0);
        const float4 wv = *(const float4*)(Wb + k0);
        __syncthreads();
        As[lc4 + 0][lr] = av.x; As[lc4 + 1][lr] = av.y;
        As[lc4 + 2][lr] = av.z; As[lc4 + 3][lr] = av.w;
        Bs[lc4 + 0][lr] = wv.x; Bs[lc4 + 1][lr] = wv.y;
        Bs[lc4 + 2][lr] = wv.z; Bs[lc4 + 3][lr] = wv.w;
        __syncthreads();
#pragma unroll
        for (int k = 0; k < 16; ++k) {
            const float4 a  = *(const float4*)&As[k][ty * 4];
            const float4 bq = *(const float4*)&Bs[k][tx * 4];
            c[0][0] += a.x * bq.x; c[0][1] += a.x * bq.y; c[0][2] += a.x * bq.z; c[0][3] += a.x * bq.w;
            c[1][0] += a.y * bq.x; c[1][1] += a.y * bq.y; c[1][2] += a.y * bq.z; c[1][3] += a.y * bq.w;
            c[2][0] += a.z * bq.x; c[2][1] += a.z * bq.y; c[2][2] += a.z * bq.z; c[2][3] += a.z * bq.w;
            c[3][0] += a.w * bq.x; c[3][1] += a.w * bq.y; c[3][2] += a.w * bq.z; c[3][3] += a.w * bq.w;
        }
    }
    const int n0 = bx * 64 + tx * 4;
    const int m0 = by * 64 + ty * 4;
    const float4 bb = *(const float4*)(bias + n0);
#pragma unroll
    for (int i = 0; i < 4; ++i) {
        const size_t off = (size_t)(m0 + i) * N + n0;
        float4 o = make_float4(c[i][0] + bb.x, c[i][1] + bb.y,
                               c[i][2] + bb.z, c[i][3] + bb.w);
        if (resid) {
            const float4 rv = *(const float4*)(resid + off);
            o.x += rv.x; o.y += rv.y; o.z += rv.z; o.w += rv.w;
        }
        *(float4*)(C + off) = o;
    }
}

// ---------------------------------------------------------------------------
// 4) GRU recurrent layer, v3: 256 WGs (16 per batch). WG (b,p) owns hidden
//    dims [32p, 32p+32) -> 96 weight rows, STAGED ONCE into LDS (96 KB f16).
//    h exchanged as packed f16 pairs through a double-buffered global buffer;
//    per-WG flag words (RELEASE store, no RMW) signal step completion.
//    Inner dot uses v_dot2_f32_f16 (fp32 accumulate). The recurrence's
//    z-blend h stays fp32 in a register (thread owns its dim for all steps),
//    so f16 only touches the matvec inputs, not the carried state.
//
//    Ordering: all h stores for a WG are issued by wave 0; the RELEASE flag
//    store (also wave 0) waits vmcnt(0) for that wave, so h is at the
//    coherence point before the flag. Consumers ACQUIRE-poll the 16 flags,
//    then RELAXED-agent load h. Double buffer (write t&1, read (t-1)&1):
//    flags >= t implies every WG finished reading buffer (t-2)&1 == t&1.
// ---------------------------------------------------------------------------
__global__ __launch_bounds__(256) void gru_layer3_kernel(
        const float*        __restrict__ xW,    // (S*B, 1536), row = t*16+b
        const unsigned int* __restrict__ Wp,    // (256, 1536) packed f16 pairs
        const float*        __restrict__ b_hh,  // (1536)
        float*              __restrict__ ys,    // (S*B, 512)
        unsigned int*       __restrict__ hbuf,  // (B, 2, 256) packed f16 pairs
        int*                __restrict__ hflag) // (B, 16), pre-zeroed
{
    extern __shared__ unsigned int smem[];
    unsigned int* wlds = smem;                 // 96*256 dwords (96 KB)
    unsigned int* hls  = smem + 96 * 256;      // 256 dwords (h packed f16x2)
    float*        dots = (float*)(smem + 96 * 256 + 256);  // 96 floats

    const int wg  = blockIdx.x;
    const int b   = wg & 15;
    const int p   = wg >> 4;                   // 0..15
    const int tid = threadIdx.x;               // 0..255

    // ---- stage this WG's 96-row weight slice into LDS (once) ----
    // LDS layout: wlds[k2*96 + c], c = gate*32 + jl
    for (int idx = tid; idx < 96 * 256; idx += 256) {
        const int k2 = idx / 96;
        const int c  = idx - k2 * 96;
        const int g  = c >> 5;
        const int jl = c & 31;
        wlds[idx] = Wp[(size_t)k2 * H3 + g * HH + p * 32 + jl];
    }

    // dot-thread assignment: tid = 2*r + half, r = gate*32 + jl (tid<192)
    const int r    = tid >> 1;
    const int half = tid & 1;
    const int gate = r >> 5;
    const int jl   = r & 31;
    const float bias = (tid < 192) ? b_hh[gate * HH + p * 32 + jl] : 0.f;

    float h_own = 0.f;                         // fp32 carried h (tid<32)
    __syncthreads();

    for (int t = 0; t < SS; ++t) {
        const int row = t * BB + b;
        // prefetch xW for this step (consumed after the dots)
        float xr = 0.f, xz = 0.f, xn = 0.f;
        if (tid < 32) {
            const int j = p * 32 + tid;
            xr = xW[(size_t)row * H3 + j];
            xz = xW[(size_t)row * H3 + HH + j];
            xn = xW[(size_t)row * H3 + 2 * HH + j];
        }

        // ---- obtain h_{t-1} (packed f16) into LDS ----
        if (t > 0) {
            if (tid < 64) {
                const int* fp = hflag + b * GPB + (tid & 15);
                for (;;) {
                    const int v = __hip_atomic_load(fp, __ATOMIC_ACQUIRE,
                                                    __HIP_MEMORY_SCOPE_AGENT);
                    if (__all(v >= t)) break;
                    __builtin_amdgcn_s_sleep(1);
                }
            }
            __syncthreads();
            const unsigned int* src = hbuf + ((size_t)b * 2 + ((t - 1) & 1)) * 256;
            hls[tid] = __hip_atomic_load(src + tid, __ATOMIC_RELAXED,
                                         __HIP_MEMORY_SCOPE_AGENT);
        } else {
            hls[tid] = 0u;
        }
        __syncthreads();

        // ---- 96 dots of length 512 via v_dot2_f32_f16 ----
        if (tid < 192) {
            float acc = 0.f;
            const int wbase = half * 128 * 96 + r;
            const int hbase = half * 128;
#pragma unroll 16
            for (int i = 0; i < 128; ++i) {
                acc = __builtin_amdgcn_fdot2(u2h2(wlds[wbase + i * 96]),
                                             u2h2(hls[hbase + i]), acc, false);
            }
            acc += __shfl_xor(acc, 1, 64);     // combine k-halves
            if (half == 0) dots[r] = acc + bias;
        }
        __syncthreads();

        // ---- gate math + h update for this WG's 32 dims (wave 0) ----
        if (tid < 32) {
            const float ar = dots[tid];
            const float az = dots[32 + tid];
            const float an = dots[64 + tid];
            const float rg = 1.f / (1.f + __expf(-(xr + ar)));
            const float zg = 1.f / (1.f + __expf(-(xz + az)));
            const float nn = xn + rg * an;
            const float e  = __expf(-2.f * nn);
            const float ng = (1.f - e) / (1.f + e);          // tanh
            const float hnew = (1.f - zg) * ng + zg * h_own;
            h_own = hnew;
            const int j = p * 32 + tid;
            ys[(size_t)row * HH + j] = hnew;
            const float other = __shfl_xor(hnew, 1, 64);
            if ((tid & 1) == 0) {
                const unsigned int pk = (unsigned int)f2h(hnew)
                                      | ((unsigned int)f2h(other) << 16);
                __hip_atomic_store(
                    hbuf + ((size_t)b * 2 + (t & 1)) * 256 + p * 16 + (tid >> 1),
                    pk, __ATOMIC_RELAXED, __HIP_MEMORY_SCOPE_AGENT);
            }
        }
        // flag: RELEASE (same wave as the h stores -> vmcnt(0) covers them)
        if (tid == 0)
            __hip_atomic_store(hflag + b * GPB + p, t + 1, __ATOMIC_RELEASE,
                               __HIP_MEMORY_SCOPE_AGENT);
        __syncthreads();   // protect dots/hls reuse next step
    }
}

// ---------------------------------------------------------------------------
// 5) Fused LayerNorm + classification head. One WG per output row.
//    Input layout (S,B,D) row s*16+b; output row r = b*64+s.
// ---------------------------------------------------------------------------
__global__ __launch_bounds__(256) void ln_head_kernel(
        const float* __restrict__ X,      // (S*B, D), row = s*16+b
        const float* __restrict__ gamma,
        const float* __restrict__ beta,
        const float* __restrict__ Wh,     // (3, 1024)
        const float* __restrict__ bh,     // (3)
        float*       __restrict__ out)    // (B*S, 3)
{
    __shared__ float red[12];
    const int r  = blockIdx.x;            // b*64 + s
    const int bI = r >> 6;
    const int s  = r & 63;
    const float* x = X + (size_t)(s * BB + bI) * DD;
    const int tid = threadIdx.x;
    const float4 v = *(const float4*)(x + tid * 4);
    float sum = v.x + v.y + v.z + v.w;
    float ss  = v.x * v.x + v.y * v.y + v.z * v.z + v.w * v.w;
#pragma unroll
    for (int o = 32; o > 0; o >>= 1) {
        sum += __shfl_down(sum, o, 64);
        ss  += __shfl_down(ss,  o, 64);
    }
    const int lane = tid & 63, w = tid >> 6;
    if (lane == 0) { red[w] = sum; red[4 + w] = ss; }
    __syncthreads();
    const float tsum = red[0] + red[1] + red[2] + red[3];
    const float tss  = red[4] + red[5] + red[6] + red[7];
    const float mu  = tsum * (1.f / (float)DD);
    const float var = tss * (1.f / (float)DD) - mu * mu;
    const float inv = rsqrtf(var + 1e-5f);
    const float4 g  = *(const float4*)(gamma + tid * 4);
    const float4 be = *(const float4*)(beta + tid * 4);
    float y0 = (v.x - mu) * inv * g.x + be.x;
    float y1 = (v.y - mu) * inv * g.y + be.y;
    float y2 = (v.z - mu) * inv * g.z + be.z;
    float y3 = (v.w - mu) * inv * g.w + be.w;
    const float4 w0 = *(const float4*)(Wh + 0 * DD + tid * 4);
    const float4 w1 = *(const float4*)(Wh + 1 * DD + tid * 4);
    const float4 w2 = *(const float4*)(Wh + 2 * DD + tid * 4);
    float p0 = y0 * w0.x + y1 * w0.y + y2 * w0.z + y3 * w0.w;
    float p1 = y0 * w1.x + y1 * w1.y + y2 * w1.z + y3 * w1.w;
    float p2 = y0 * w2.x + y1 * w2.y + y2 * w2.z + y3 * w2.w;
#pragma unroll
    for (int o = 32; o > 0; o >>= 1) {
        p0 += __shfl_down(p0, o, 64);
        p1 += __shfl_down(p1, o, 64);
        p2 += __shfl_down(p2, o, 64);
    }
    __syncthreads();   // red reuse
    if (lane == 0) { red[w] = p0; red[4 + w] = p1; red[8 + w] = p2; }
    __syncthreads();
    if (tid == 0) {
        out[(size_t)r * NCLS + 0] = red[0] + red[1] + red[2]  + red[3]  + bh[0];
        out[(size_t)r * NCLS + 1] = red[4] + red[5] + red[6]  + red[7]  + bh[1];
        out[(size_t)r * NCLS + 2] = red[8] + red[9] + red[10] + red[11] + bh[2];
    }
}

// ---------------------------------------------------------------------------
extern "C" void kernel_launch(void* const* d_in, const int* in_sizes, int n_in,
                              void* d_out, int out_size, void* d_ws, size_t ws_size,
                              hipStream_t stream) {
    const float* hs      = (const float*)d_in[0];
    const float* W_down  = (const float*)d_in[1];
    const float* b_down  = (const float*)d_in[2];
    const float* W_ih0   = (const float*)d_in[3];
    const float* W_hh0   = (const float*)d_in[4];
    const float* b_ih0   = (const float*)d_in[5];
    const float* b_hh0   = (const float*)d_in[6];
    const float* W_ih1   = (const float*)d_in[7];
    const float* W_hh1   = (const float*)d_in[8];
    const float* b_ih1   = (const float*)d_in[9];
    const float* b_hh1   = (const float*)d_in[10];
    const float* W_lin1  = (const float*)d_in[11];
    const float* b_lin1  = (const float*)d_in[12];
    const float* gamma   = (const float*)d_in[13];
    const float* beta    = (const float*)d_in[14];
    const float* W_head  = (const float*)d_in[15];
    const float* b_head  = (const float*)d_in[16];
    const int*   gidx    = (const int*)d_in[17];
    float* out = (float*)d_out;

    char* ws = (char*)d_ws;
    float* pooled = (float*)(ws);                         // 4 MB  (1024x1024)
    float* xd     = (float*)(ws + ((size_t)4  << 20));    // 2 MB  (1024x512)
    float* xW     = (float*)(ws + ((size_t)6  << 20));    // 6 MB  (1024x1536)
    float* ys0    = (float*)(ws + ((size_t)12 << 20));    // 2 MB
    float* ys1    = (float*)(ws + ((size_t)14 << 20));    // 2 MB
    float* xln    = (float*)(ws + ((size_t)16 << 20));    // 4 MB
    unsigned int* wp0 = (unsigned int*)(ws + ((size_t)20 << 20)); // 1.5 MB
    unsigned int* wp1 = (unsigned int*)(ws + ((size_t)22 << 20)); // 1.5 MB
    unsigned int* hbuf  = (unsigned int*)(ws + ((size_t)23 << 20) + (512 << 10)); // 32 KB
    int*          hflag = (int*)(ws + ((size_t)23 << 20) + (640 << 10));          // 2*256 ints

    // zero the flags (ws is poisoned before every launch)
    hipMemsetAsync(hflag, 0, 2 * BB * GPB * sizeof(int), stream);

    // 1) pooling (also the residual source), layout (S,B,D)
    pool_kernel<<<BB * SS, 256, 0, stream>>>(hs, gidx, pooled);

    // 2) pack recurrent weights (f16 k-pairs, k-major)
    pack_whh_kernel<<<dim3(HH / 32, H3 / 32), dim3(32, 8), 0, stream>>>(W_hh0, wp0);
    pack_whh_kernel<<<dim3(HH / 32, H3 / 32), dim3(32, 8), 0, stream>>>(W_hh1, wp1);

    // 3) down-projection: xd = pooled @ W_down^T + b_down
    gemm_tn_kernel<<<dim3(HH / 64, (SS * BB) / 64), 256, 0, stream>>>(
        pooled, W_down, b_down, nullptr, xd, SS * BB, HH, DD);

    // 4) layer-0 input projection: xW = xd @ W_ih0^T + b_ih0
    gemm_tn_kernel<<<dim3(H3 / 64, (SS * BB) / 64), 256, 0, stream>>>(
        xd, W_ih0, b_ih0, nullptr, xW, SS * BB, H3, HH);

    const size_t gru_smem = (96 * 256 + 256 + 96) * sizeof(unsigned int);

    // 5) layer-0 recurrence
    gru_layer3_kernel<<<BB * GPB, 256, gru_smem, stream>>>(
        xW, wp0, b_hh0, ys0, hbuf, hflag);

    // 6) layer-1 input projection
    gemm_tn_kernel<<<dim3(H3 / 64, (SS * BB) / 64), 256, 0, stream>>>(
        ys0, W_ih1, b_ih1, nullptr, xW, SS * BB, H3, HH);

    // 7) layer-1 recurrence (fresh flag block)
    gru_layer3_kernel<<<BB * GPB, 256, gru_smem, stream>>>(
        xW, wp1, b_hh1, ys1, hbuf, hflag + BB * GPB);

    // 8) up-projection + residual: xln = pooled + ys1 @ W_lin1^T + b_lin1
    gemm_tn_kernel<<<dim3(DD / 64, (SS * BB) / 64), 256, 0, stream>>>(
        ys1, W_lin1, b_lin1, pooled, xln, SS * BB, DD, HH);

    // 9) LayerNorm + head
    ln_head_kernel<<<BB * SS, 256, 0, stream>>>(xln, gamma, beta, W_head, b_head, out);
}

// Round 4
// 870.949 us; speedup vs baseline: 3.0710x; 1.6090x over previous
//
#include <hip/hip_runtime.h>
#include <hip/hip_bf16.h>
#include <cstddef>

// Problem constants
#define BB   16
#define LL   2048
#define DD   1024
#define SS   64
#define HH   512
#define H3   1536
#define NCLS 3
#define GPB  16   // WGs per batch in the GRU (each owns 32 of 512 hidden dims)

typedef _Float16 half2_t __attribute__((ext_vector_type(2)));

static __device__ __forceinline__ half2_t u2h2(unsigned int u) {
    union { unsigned int u; half2_t h; } cv; cv.u = u; return cv.h;
}
static __device__ __forceinline__ unsigned short f2h(float f) {
    _Float16 h = (_Float16)f;
    union { _Float16 h; unsigned short u; } cv; cv.h = h; return cv.u;
}

// ---------------------------------------------------------------------------
// 1) Segment-mean pooling. One WG per (s,b) pair; output layout (S,B,D),
//    row r = s*16 + b  (the layout the GRU wants).
// ---------------------------------------------------------------------------
__global__ __launch_bounds__(256) void pool_kernel(
        const float* __restrict__ hs,      // (B, L, D)
        const int*   __restrict__ gidx,    // (B, L)
        float*       __restrict__ pooled)  // (S*B, D), row = s*16+b
{
    const int r = blockIdx.x;
    const int b = r & 15;
    const int s = r >> 4;
    __shared__ int lst[LL];
    __shared__ int cnt;
    const int tid = threadIdx.x;
    if (tid == 0) cnt = 0;
    __syncthreads();
    const int* gi = gidx + b * LL;
    for (int l = tid; l < LL; l += 256) {
        if (gi[l] == s) { int p = atomicAdd(&cnt, 1); lst[p] = l; }
    }
    __syncthreads();
    const int c = cnt;
    const float* hb = hs + (size_t)b * LL * DD;
    const int d0 = tid * 4;
    float4 acc = make_float4(0.f, 0.f, 0.f, 0.f);
    for (int i = 0; i < c; ++i) {
        const float4 v = *(const float4*)(hb + (size_t)lst[i] * DD + d0);
        acc.x += v.x; acc.y += v.y; acc.z += v.z; acc.w += v.w;
    }
    const float inv = 1.0f / (float)c;
    float4 o = make_float4(acc.x * inv, acc.y * inv, acc.z * inv, acc.w * inv);
    *(float4*)(pooled + (size_t)r * DD + d0) = o;
}

// ---------------------------------------------------------------------------
// 2) Transpose + f16-pack W_hh (1536x512) -> Wp (256 x 1536) of uint32,
//    Wp[k2*1536 + g] packs f16(W[g][2k2]) (lo) and f16(W[g][2k2+1]) (hi).
// ---------------------------------------------------------------------------
__global__ __launch_bounds__(256) void pack_whh_kernel(
        const float* __restrict__ W,       // (1536, 512)
        unsigned int* __restrict__ Wp)     // (256, 1536)
{
    __shared__ float t[32][33];
    const int k0 = blockIdx.x * 32;        // 0..480
    const int g0 = blockIdx.y * 32;        // 0..1504
    const int tx = threadIdx.x;            // 0..31
    const int ty = threadIdx.y;            // 0..7
    for (int i = ty; i < 32; i += 8)
        t[i][tx] = W[(size_t)(g0 + i) * HH + k0 + tx];   // t[g_local][k_local]
    __syncthreads();
    for (int i = ty; i < 16; i += 8) {
        const float lo = t[tx][2 * i];
        const float hi = t[tx][2 * i + 1];
        const unsigned int p = (unsigned int)f2h(lo) | ((unsigned int)f2h(hi) << 16);
        Wp[(size_t)(k0 / 2 + i) * H3 + g0 + tx] = p;
    }
}

// ---------------------------------------------------------------------------
// 3) fp32 GEMM: C[M,N] = A[M,K] @ W[N,K]^T + bias[N] (+ resid[M,N]).
//    64x64 tile, BK=16, 256 threads, 4x4 per thread.
// ---------------------------------------------------------------------------
__global__ __launch_bounds__(256) void gemm_tn_kernel(
        const float* __restrict__ A,
        const float* __restrict__ W,
        const float* __restrict__ bias,
        const float* __restrict__ resid,   // nullable
        float*       __restrict__ C,
        int M, int N, int K)
{
    __shared__ float As[16][68];
    __shared__ float Bs[16][68];
    const int tid = threadIdx.x;
    const int tx = tid & 15, ty = tid >> 4;
    const int bx = blockIdx.x, by = blockIdx.y;
    const int lr  = tid >> 2;          // 0..63
    const int lc4 = (tid & 3) * 4;     // 0,4,8,12
    const float* Ab = A + (size_t)(by * 64 + lr) * K + lc4;
    const float* Wb = W + (size_t)(bx * 64 + lr) * K + lc4;
    float c[4][4] = {};
    for (int k0 = 0; k0 < K; k0 += 16) {
        const float4 av = *(const float4*)(Ab + k0);
        const float4 wv = *(const float4*)(Wb + k0);
        __syncthreads();
        As[lc4 + 0][lr] = av.x; As[lc4 + 1][lr] = av.y;
        As[lc4 + 2][lr] = av.z; As[lc4 + 3][lr] = av.w;
        Bs[lc4 + 0][lr] = wv.x; Bs[lc4 + 1][lr] = wv.y;
        Bs[lc4 + 2][lr] = wv.z; Bs[lc4 + 3][lr] = wv.w;
        __syncthreads();
#pragma unroll
        for (int k = 0; k < 16; ++k) {
            const float4 a  = *(const float4*)&As[k][ty * 4];
            const float4 bq = *(const float4*)&Bs[k][tx * 4];
            c[0][0] += a.x * bq.x; c[0][1] += a.x * bq.y; c[0][2] += a.x * bq.z; c[0][3] += a.x * bq.w;
            c[1][0] += a.y * bq.x; c[1][1] += a.y * bq.y; c[1][2] += a.y * bq.z; c[1][3] += a.y * bq.w;
            c[2][0] += a.z * bq.x; c[2][1] += a.z * bq.y; c[2][2] += a.z * bq.z; c[2][3] += a.z * bq.w;
            c[3][0] += a.w * bq.x; c[3][1] += a.w * bq.y; c[3][2] += a.w * bq.z; c[3][3] += a.w * bq.w;
        }
    }
    const int n0 = bx * 64 + tx * 4;
    const int m0 = by * 64 + ty * 4;
    const float4 bb = *(const float4*)(bias + n0);
#pragma unroll
    for (int i = 0; i < 4; ++i) {
        const size_t off = (size_t)(m0 + i) * N + n0;
        float4 o = make_float4(c[i][0] + bb.x, c[i][1] + bb.y,
                               c[i][2] + bb.z, c[i][3] + bb.w);
        if (resid) {
            const float4 rv = *(const float4*)(resid + off);
            o.x += rv.x; o.y += rv.y; o.z += rv.z; o.w += rv.w;
        }
        *(float4*)(C + off) = o;
    }
}

// ---------------------------------------------------------------------------
// 4) GRU recurrent layer, v4: identical structure to v3 (16 WGs/batch,
//    96 KB f16 weight slice LDS-resident, fdot2 dots, fp32 carried h)
//    EXCEPT the cross-WG sync uses only RELAXED agent-scope atomics.
//
//    Rationale: agent-scope ACQUIRE/RELEASE on gfx950 lower to buffer_inv /
//    buffer_wbl2 (whole-XCD L2 invalidate/writeback) -- we were paying one
//    L2 writeback per producer step and one L2 invalidate PER POLL ITERATION.
//    All exchanged data (hbuf, hflag) is accessed exclusively with sc1
//    (cache-bypassing) atomic ops, so no stale cached copies can exist;
//    ordering needs only:
//      producer: h stores (wave 0) -> s_waitcnt vmcnt(0) -> flag store
//                (same wave, so the waitcnt covers the h stores)
//      consumer: flag poll -> __syncthreads (compiler+hw fence) -> h loads
// ---------------------------------------------------------------------------
__global__ __launch_bounds__(256) void gru_layer4_kernel(
        const float*        __restrict__ xW,    // (S*B, 1536), row = t*16+b
        const unsigned int* __restrict__ Wp,    // (256, 1536) packed f16 pairs
        const float*        __restrict__ b_hh,  // (1536)
        float*              __restrict__ ys,    // (S*B, 512)
        unsigned int*       __restrict__ hbuf,  // (B, 2, 256) packed f16 pairs
        int*                __restrict__ hflag) // (B, 16), pre-zeroed
{
    extern __shared__ unsigned int smem[];
    unsigned int* wlds = smem;                 // 96*256 dwords (96 KB)
    unsigned int* hls  = smem + 96 * 256;      // 256 dwords (h packed f16x2)
    float*        dots = (float*)(smem + 96 * 256 + 256);  // 96 floats

    const int wg  = blockIdx.x;
    const int b   = wg & 15;
    const int p   = wg >> 4;                   // 0..15
    const int tid = threadIdx.x;               // 0..255

    // ---- stage this WG's 96-row weight slice into LDS (once) ----
    // LDS layout: wlds[k2*96 + c], c = gate*32 + jl
    for (int idx = tid; idx < 96 * 256; idx += 256) {
        const int k2 = idx / 96;
        const int c  = idx - k2 * 96;
        const int g  = c >> 5;
        const int jl = c & 31;
        wlds[idx] = Wp[(size_t)k2 * H3 + g * HH + p * 32 + jl];
    }

    // dot-thread assignment: tid = 2*r + half, r = gate*32 + jl (tid<192)
    const int r    = tid >> 1;
    const int half = tid & 1;
    const int gate = r >> 5;
    const int jl   = r & 31;
    const float bias = (tid < 192) ? b_hh[gate * HH + p * 32 + jl] : 0.f;

    float h_own = 0.f;                         // fp32 carried h (tid<32)
    __syncthreads();

    for (int t = 0; t < SS; ++t) {
        const int row = t * BB + b;
        // prefetch xW for this step (consumed after the dots)
        float xr = 0.f, xz = 0.f, xn = 0.f;
        if (tid < 32) {
            const int j = p * 32 + tid;
            xr = xW[(size_t)row * H3 + j];
            xz = xW[(size_t)row * H3 + HH + j];
            xn = xW[(size_t)row * H3 + 2 * HH + j];
        }

        // ---- obtain h_{t-1} (packed f16) into LDS ----
        if (t > 0) {
            if (tid < 64) {
                const int* fp = hflag + b * GPB + (tid & 15);
                for (;;) {
                    const int v = __hip_atomic_load(fp, __ATOMIC_RELAXED,
                                                    __HIP_MEMORY_SCOPE_AGENT);
                    if (__all(v >= t)) break;
                    __builtin_amdgcn_s_sleep(1);
                }
            }
            __syncthreads();   // fence: no h load issues before flags observed
            const unsigned int* src = hbuf + ((size_t)b * 2 + ((t - 1) & 1)) * 256;
            hls[tid] = __hip_atomic_load(src + tid, __ATOMIC_RELAXED,
                                         __HIP_MEMORY_SCOPE_AGENT);
        } else {
            hls[tid] = 0u;
        }
        __syncthreads();

        // ---- 96 dots of length 512 via v_dot2_f32_f16 ----
        if (tid < 192) {
            float acc = 0.f;
            const int wbase = half * 128 * 96 + r;
            const int hbase = half * 128;
#pragma unroll 16
            for (int i = 0; i < 128; ++i) {
                acc = __builtin_amdgcn_fdot2(u2h2(wlds[wbase + i * 96]),
                                             u2h2(hls[hbase + i]), acc, false);
            }
            acc += __shfl_xor(acc, 1, 64);     // combine k-halves
            if (half == 0) dots[r] = acc + bias;
        }
        __syncthreads();

        // ---- gate math + h update for this WG's 32 dims (wave 0) ----
        if (tid < 32) {
            const float ar = dots[tid];
            const float az = dots[32 + tid];
            const float an = dots[64 + tid];
            const float rg = 1.f / (1.f + __expf(-(xr + ar)));
            const float zg = 1.f / (1.f + __expf(-(xz + az)));
            const float nn = xn + rg * an;
            const float e  = __expf(-2.f * nn);
            const float ng = (1.f - e) / (1.f + e);          // tanh
            const float hnew = (1.f - zg) * ng + zg * h_own;
            h_own = hnew;
            const int j = p * 32 + tid;
            ys[(size_t)row * HH + j] = hnew;
            const float other = __shfl_xor(hnew, 1, 64);
            if ((tid & 1) == 0) {
                const unsigned int pk = (unsigned int)f2h(hnew)
                                      | ((unsigned int)f2h(other) << 16);
                __hip_atomic_store(
                    hbuf + ((size_t)b * 2 + (t & 1)) * 256 + p * 16 + (tid >> 1),
                    pk, __ATOMIC_RELAXED, __HIP_MEMORY_SCOPE_AGENT);
            }
        }
        // flag store: same wave as the h stores; explicit vmcnt(0) drain
        // orders h stores before the flag at the coherence point. No L2
        // cache maintenance needed (hbuf/hflag only touched via sc1 ops).
        if (tid == 0) {
            __builtin_amdgcn_s_waitcnt(0);
            __hip_atomic_store(hflag + b * GPB + p, t + 1, __ATOMIC_RELAXED,
                               __HIP_MEMORY_SCOPE_AGENT);
        }
        __syncthreads();   // protect dots/hls reuse next step
    }
}

// ---------------------------------------------------------------------------
// 5) Fused LayerNorm + classification head. One WG per output row.
//    Input layout (S,B,D) row s*16+b; output row r = b*64+s.
// ---------------------------------------------------------------------------
__global__ __launch_bounds__(256) void ln_head_kernel(
        const float* __restrict__ X,      // (S*B, D), row = s*16+b
        const float* __restrict__ gamma,
        const float* __restrict__ beta,
        const float* __restrict__ Wh,     // (3, 1024)
        const float* __restrict__ bh,     // (3)
        float*       __restrict__ out)    // (B*S, 3)
{
    __shared__ float red[12];
    const int r  = blockIdx.x;            // b*64 + s
    const int bI = r >> 6;
    const int s  = r & 63;
    const float* x = X + (size_t)(s * BB + bI) * DD;
    const int tid = threadIdx.x;
    const float4 v = *(const float4*)(x + tid * 4);
    float sum = v.x + v.y + v.z + v.w;
    float ss  = v.x * v.x + v.y * v.y + v.z * v.z + v.w * v.w;
#pragma unroll
    for (int o = 32; o > 0; o >>= 1) {
        sum += __shfl_down(sum, o, 64);
        ss  += __shfl_down(ss,  o, 64);
    }
    const int lane = tid & 63, w = tid >> 6;
    if (lane == 0) { red[w] = sum; red[4 + w] = ss; }
    __syncthreads();
    const float tsum = red[0] + red[1] + red[2] + red[3];
    const float tss  = red[4] + red[5] + red[6] + red[7];
    const float mu  = tsum * (1.f / (float)DD);
    const float var = tss * (1.f / (float)DD) - mu * mu;
    const float inv = rsqrtf(var + 1e-5f);
    const float4 g  = *(const float4*)(gamma + tid * 4);
    const float4 be = *(const float4*)(beta + tid * 4);
    float y0 = (v.x - mu) * inv * g.x + be.x;
    float y1 = (v.y - mu) * inv * g.y + be.y;
    float y2 = (v.z - mu) * inv * g.z + be.z;
    float y3 = (v.w - mu) * inv * g.w + be.w;
    const float4 w0 = *(const float4*)(Wh + 0 * DD + tid * 4);
    const float4 w1 = *(const float4*)(Wh + 1 * DD + tid * 4);
    const float4 w2 = *(const float4*)(Wh + 2 * DD + tid * 4);
    float p0 = y0 * w0.x + y1 * w0.y + y2 * w0.z + y3 * w0.w;
    float p1 = y0 * w1.x + y1 * w1.y + y2 * w1.z + y3 * w1.w;
    float p2 = y0 * w2.x + y1 * w2.y + y2 * w2.z + y3 * w2.w;
#pragma unroll
    for (int o = 32; o > 0; o >>= 1) {
        p0 += __shfl_down(p0, o, 64);
        p1 += __shfl_down(p1, o, 64);
        p2 += __shfl_down(p2, o, 64);
    }
    __syncthreads();   // red reuse
    if (lane == 0) { red[w] = p0; red[4 + w] = p1; red[8 + w] = p2; }
    __syncthreads();
    if (tid == 0) {
        out[(size_t)r * NCLS + 0] = red[0] + red[1] + red[2]  + red[3]  + bh[0];
        out[(size_t)r * NCLS + 1] = red[4] + red[5] + red[6]  + red[7]  + bh[1];
        out[(size_t)r * NCLS + 2] = red[8] + red[9] + red[10] + red[11] + bh[2];
    }
}

// ---------------------------------------------------------------------------
extern "C" void kernel_launch(void* const* d_in, const int* in_sizes, int n_in,
                              void* d_out, int out_size, void* d_ws, size_t ws_size,
                              hipStream_t stream) {
    const float* hs      = (const float*)d_in[0];
    const float* W_down  = (const float*)d_in[1];
    const float* b_down  = (const float*)d_in[2];
    const float* W_ih0   = (const float*)d_in[3];
    const float* W_hh0   = (const float*)d_in[4];
    const float* b_ih0   = (const float*)d_in[5];
    const float* b_hh0   = (const float*)d_in[6];
    const float* W_ih1   = (const float*)d_in[7];
    const float* W_hh1   = (const float*)d_in[8];
    const float* b_ih1   = (const float*)d_in[9];
    const float* b_hh1   = (const float*)d_in[10];
    const float* W_lin1  = (const float*)d_in[11];
    const float* b_lin1  = (const float*)d_in[12];
    const float* gamma   = (const float*)d_in[13];
    const float* beta    = (const float*)d_in[14];
    const float* W_head  = (const float*)d_in[15];
    const float* b_head  = (const float*)d_in[16];
    const int*   gidx    = (const int*)d_in[17];
    float* out = (float*)d_out;

    char* ws = (char*)d_ws;
    float* pooled = (float*)(ws);                         // 4 MB  (1024x1024)
    float* xd     = (float*)(ws + ((size_t)4  << 20));    // 2 MB  (1024x512)
    float* xW     = (float*)(ws + ((size_t)6  << 20));    // 6 MB  (1024x1536)
    float* ys0    = (float*)(ws + ((size_t)12 << 20));    // 2 MB
    float* ys1    = (float*)(ws + ((size_t)14 << 20));    // 2 MB
    float* xln    = (float*)(ws + ((size_t)16 << 20));    // 4 MB
    unsigned int* wp0 = (unsigned int*)(ws + ((size_t)20 << 20)); // 1.5 MB
    unsigned int* wp1 = (unsigned int*)(ws + ((size_t)22 << 20)); // 1.5 MB
    unsigned int* hbuf  = (unsigned int*)(ws + ((size_t)23 << 20) + (512 << 10)); // 32 KB
    int*          hflag = (int*)(ws + ((size_t)23 << 20) + (640 << 10));          // 2*256 ints

    // zero the flags (ws is poisoned before every launch)
    hipMemsetAsync(hflag, 0, 2 * BB * GPB * sizeof(int), stream);

    // 1) pooling (also the residual source), layout (S,B,D)
    pool_kernel<<<BB * SS, 256, 0, stream>>>(hs, gidx, pooled);

    // 2) pack recurrent weights (f16 k-pairs, k-major)
    pack_whh_kernel<<<dim3(HH / 32, H3 / 32), dim3(32, 8), 0, stream>>>(W_hh0, wp0);
    pack_whh_kernel<<<dim3(HH / 32, H3 / 32), dim3(32, 8), 0, stream>>>(W_hh1, wp1);

    // 3) down-projection: xd = pooled @ W_down^T + b_down
    gemm_tn_kernel<<<dim3(HH / 64, (SS * BB) / 64), 256, 0, stream>>>(
        pooled, W_down, b_down, nullptr, xd, SS * BB, HH, DD);

    // 4) layer-0 input projection: xW = xd @ W_ih0^T + b_ih0
    gemm_tn_kernel<<<dim3(H3 / 64, (SS * BB) / 64), 256, 0, stream>>>(
        xd, W_ih0, b_ih0, nullptr, xW, SS * BB, H3, HH);

    const size_t gru_smem = (96 * 256 + 256 + 96) * sizeof(unsigned int);

    // 5) layer-0 recurrence
    gru_layer4_kernel<<<BB * GPB, 256, gru_smem, stream>>>(
        xW, wp0, b_hh0, ys0, hbuf, hflag);

    // 6) layer-1 input projection
    gemm_tn_kernel<<<dim3(H3 / 64, (SS * BB) / 64), 256, 0, stream>>>(
        ys0, W_ih1, b_ih1, nullptr, xW, SS * BB, H3, HH);

    // 7) layer-1 recurrence (fresh flag block)
    gru_layer4_kernel<<<BB * GPB, 256, gru_smem, stream>>>(
        xW, wp1, b_hh1, ys1, hbuf, hflag + BB * GPB);

    // 8) up-projection + residual: xln = pooled + ys1 @ W_lin1^T + b_lin1
    gemm_tn_kernel<<<dim3(DD / 64, (SS * BB) / 64), 256, 0, stream>>>(
        ys1, W_lin1, b_lin1, pooled, xln, SS * BB, DD, HH);

    // 9) LayerNorm + head
    ln_head_kernel<<<BB * SS, 256, 0, stream>>>(xln, gamma, beta, W_head, b_head, out);
}

// Round 5
// 660.534 us; speedup vs baseline: 4.0493x; 1.3186x over previous
//
#include <hip/hip_runtime.h>
#include <hip/hip_bf16.h>
#include <cstddef>

// Problem constants
#define BB   16
#define LL   2048
#define DD   1024
#define SS   64
#define HH   512
#define H3   1536
#define NCLS 3
#define GPB  16   // WGs per batch in the GRU (each owns 32 of 512 hidden dims)

typedef _Float16 half2_t __attribute__((ext_vector_type(2)));
typedef _Float16 f16x8  __attribute__((ext_vector_type(8)));
typedef float    f32x4  __attribute__((ext_vector_type(4)));

static __device__ __forceinline__ half2_t u2h2(unsigned int u) {
    union { unsigned int u; half2_t h; } cv; cv.u = u; return cv.h;
}
static __device__ __forceinline__ unsigned short f2h(float f) {
    _Float16 h = (_Float16)f;
    union { _Float16 h; unsigned short u; } cv; cv.h = h; return cv.u;
}

// ---------------------------------------------------------------------------
// 1) Segment-mean pooling. One WG per (s,b); output (S,B,D) row r = s*16+b,
//    in fp32 (residual) AND f16 (GEMM input).
// ---------------------------------------------------------------------------
__global__ __launch_bounds__(256) void pool_kernel(
        const float* __restrict__ hs,      // (B, L, D)
        const int*   __restrict__ gidx,    // (B, L)
        float*       __restrict__ pooled,  // (S*B, D) fp32
        _Float16*    __restrict__ pooledh) // (S*B, D) f16
{
    const int r = blockIdx.x;
    const int b = r & 15;
    const int s = r >> 4;
    __shared__ int lst[LL];
    __shared__ int cnt;
    const int tid = threadIdx.x;
    if (tid == 0) cnt = 0;
    __syncthreads();
    const int* gi = gidx + b * LL;
    for (int l = tid; l < LL; l += 256) {
        if (gi[l] == s) { int p = atomicAdd(&cnt, 1); lst[p] = l; }
    }
    __syncthreads();
    const int c = cnt;
    const float* hb = hs + (size_t)b * LL * DD;
    const int d0 = tid * 4;
    float4 acc = make_float4(0.f, 0.f, 0.f, 0.f);
    for (int i = 0; i < c; ++i) {
        const float4 v = *(const float4*)(hb + (size_t)lst[i] * DD + d0);
        acc.x += v.x; acc.y += v.y; acc.z += v.z; acc.w += v.w;
    }
    const float inv = 1.0f / (float)c;
    float4 o = make_float4(acc.x * inv, acc.y * inv, acc.z * inv, acc.w * inv);
    *(float4*)(pooled + (size_t)r * DD + d0) = o;
    ushort4 oh;
    oh.x = f2h(o.x); oh.y = f2h(o.y); oh.z = f2h(o.z); oh.w = f2h(o.w);
    *(ushort4*)(pooledh + (size_t)r * DD + d0) = oh;
}

// ---------------------------------------------------------------------------
// 2) Transpose + f16-pack W_hh (1536x512) -> Wp (256 x 1536) of uint32,
//    Wp[k2*1536 + g] packs f16(W[g][2k2]) (lo) and f16(W[g][2k2+1]) (hi).
// ---------------------------------------------------------------------------
__global__ __launch_bounds__(256) void pack_whh_kernel(
        const float* __restrict__ W,       // (1536, 512)
        unsigned int* __restrict__ Wp)     // (256, 1536)
{
    __shared__ float t[32][33];
    const int k0 = blockIdx.x * 32;
    const int g0 = blockIdx.y * 32;
    const int tx = threadIdx.x;            // 0..31
    const int ty = threadIdx.y;            // 0..7
    for (int i = ty; i < 32; i += 8)
        t[i][tx] = W[(size_t)(g0 + i) * HH + k0 + tx];
    __syncthreads();
    for (int i = ty; i < 16; i += 8) {
        const float lo = t[tx][2 * i];
        const float hi = t[tx][2 * i + 1];
        const unsigned int p = (unsigned int)f2h(lo) | ((unsigned int)f2h(hi) << 16);
        Wp[(size_t)(k0 / 2 + i) * H3 + g0 + tx] = p;
    }
}

// ---------------------------------------------------------------------------
// 2b) Elementwise fp32 -> f16 convert (for GEMM weights).
// ---------------------------------------------------------------------------
__global__ __launch_bounds__(256) void cvt_f16_kernel(
        const float* __restrict__ src, _Float16* __restrict__ dst, int n)
{
    const int i = (blockIdx.x * 256 + threadIdx.x) * 8;
    if (i + 8 <= n) {
        const float4 a = *(const float4*)(src + i);
        const float4 b = *(const float4*)(src + i + 4);
        ushort4 u0, u1;
        u0.x = f2h(a.x); u0.y = f2h(a.y); u0.z = f2h(a.z); u0.w = f2h(a.w);
        u1.x = f2h(b.x); u1.y = f2h(b.y); u1.z = f2h(b.z); u1.w = f2h(b.w);
        *(ushort4*)(dst + i)     = u0;
        *(ushort4*)(dst + i + 4) = u1;
    }
}

// ---------------------------------------------------------------------------
// 3) f16 MFMA GEMM: C[M,N] = A[M,K] @ W[N,K]^T + bias[N] (+resid, fp32 out)
//    or f16 out. 64x64 tile per WG (4 waves; wave w = 16-row strip), K-step 32.
//    Fragment layouts per verified m89/m97 mappings:
//      A-frag: lane m=lane&15, k = (lane>>4)*8 + j  (16B contiguous load)
//      B-frag: lane n=lane&15, same k              (W is N-major, K-contig)
//      C/D:    col = n0 + nb*16 + (lane&15), row = m0 + (lane>>4)*4 + reg
// ---------------------------------------------------------------------------
template <bool F16OUT>
__global__ __launch_bounds__(256) void gemm_mfma_kernel(
        const _Float16* __restrict__ A,
        const _Float16* __restrict__ W,
        const float*    __restrict__ bias,
        const float*    __restrict__ resid,   // nullable, only for fp32 out
        void*           __restrict__ C,
        int M, int N, int K)
{
    const int tid  = threadIdx.x;
    const int wv   = tid >> 6;
    const int lane = tid & 63;
    const int m0 = blockIdx.y * 64 + wv * 16;
    const int n0 = blockIdx.x * 64;
    const int l15 = lane & 15;
    const int ko  = (lane >> 4) * 8;

    const _Float16* Ap = A + (size_t)(m0 + l15) * K + ko;
    const _Float16* Wp = W + (size_t)(n0 + l15) * K + ko;

    f32x4 acc[4] = {};
    for (int k0 = 0; k0 < K; k0 += 32) {
        const f16x8 a = *(const f16x8*)(Ap + k0);
#pragma unroll
        for (int nb = 0; nb < 4; ++nb) {
            const f16x8 bq = *(const f16x8*)(Wp + (size_t)nb * 16 * K + k0);
            acc[nb] = __builtin_amdgcn_mfma_f32_16x16x32_f16(a, bq, acc[nb], 0, 0, 0);
        }
    }
    const int crow = m0 + (lane >> 4) * 4;
#pragma unroll
    for (int nb = 0; nb < 4; ++nb) {
        const int col = n0 + nb * 16 + l15;
        const float bb = bias[col];
#pragma unroll
        for (int rg = 0; rg < 4; ++rg) {
            float v = acc[nb][rg] + bb;
            const size_t off = (size_t)(crow + rg) * N + col;
            if (F16OUT) {
                ((_Float16*)C)[off] = (_Float16)v;
            } else {
                if (resid) v += resid[off];
                ((float*)C)[off] = v;
            }
        }
    }
}

// ---------------------------------------------------------------------------
// 4) GRU recurrent layer, v5: same sync structure as v4 (relaxed sc1 atomics
//    + explicit vmcnt drain), but the 96-row weight slice lives in VGPRs
//    (128 dwords/thread, constant across all 64 steps) and h is read from
//    LDS with broadcast ds_read_b128. xW input and ys output are f16.
// ---------------------------------------------------------------------------
__global__ __launch_bounds__(256) void gru_layer5_kernel(
        const _Float16*     __restrict__ xW,    // (S*B, 1536) f16, row = t*16+b
        const unsigned int* __restrict__ Wp,    // (256, 1536) packed f16 pairs
        const float*        __restrict__ b_hh,  // (1536)
        _Float16*           __restrict__ ys,    // (S*B, 512) f16
        unsigned int*       __restrict__ hbuf,  // (B, 2, 256) packed f16 pairs
        int*                __restrict__ hflag) // (B, 16), pre-zeroed
{
    __shared__ __align__(16) unsigned int hls[256];  // h packed f16x2
    __shared__ float dots[96];

    const int wg  = blockIdx.x;
    const int b   = wg & 15;
    const int p   = wg >> 4;
    const int tid = threadIdx.x;

    // dot-thread assignment: tid = 2*r + half, r = gate*32 + jl (tid<192)
    const int r    = tid >> 1;
    const int half = tid & 1;
    const int gate = r >> 5;
    const int jl   = r & 31;
    const int col  = gate * HH + p * 32 + jl;

    float bias = 0.f;
    unsigned int wreg[128];                    // this thread's weight half-row
    if (tid < 192) {
        bias = b_hh[col];
#pragma unroll
        for (int i = 0; i < 128; ++i)
            wreg[i] = Wp[(size_t)(half * 128 + i) * H3 + col];
    }

    float h_own = 0.f;                         // fp32 carried h (tid<32)

    for (int t = 0; t < SS; ++t) {
        const int row = t * BB + b;
        float xr = 0.f, xz = 0.f, xn = 0.f;
        if (tid < 32) {
            const int j = p * 32 + tid;
            xr = (float)xW[(size_t)row * H3 + j];
            xz = (float)xW[(size_t)row * H3 + HH + j];
            xn = (float)xW[(size_t)row * H3 + 2 * HH + j];
        }

        // ---- obtain h_{t-1} (packed f16) into LDS ----
        if (t > 0) {
            if (tid < 64) {
                const int* fp = hflag + b * GPB + (tid & 15);
                for (;;) {
                    const int v = __hip_atomic_load(fp, __ATOMIC_RELAXED,
                                                    __HIP_MEMORY_SCOPE_AGENT);
                    if (__all(v >= t)) break;
                    __builtin_amdgcn_s_sleep(1);
                }
            }
            __syncthreads();   // no h load issues before flags observed
            const unsigned int* src = hbuf + ((size_t)b * 2 + ((t - 1) & 1)) * 256;
            hls[tid] = __hip_atomic_load(src + tid, __ATOMIC_RELAXED,
                                         __HIP_MEMORY_SCOPE_AGENT);
        } else {
            hls[tid] = 0u;
        }
        __syncthreads();

        // ---- 96 dots of length 512: register weights x broadcast-LDS h ----
        if (tid < 192) {
            float a0 = 0.f, a1 = 0.f, a2 = 0.f, a3 = 0.f;
            const uint4* hp = (const uint4*)&hls[half * 128];
#pragma unroll
            for (int i = 0; i < 32; ++i) {
                const uint4 hv = hp[i];
                a0 = __builtin_amdgcn_fdot2(u2h2(wreg[4 * i + 0]), u2h2(hv.x), a0, false);
                a1 = __builtin_amdgcn_fdot2(u2h2(wreg[4 * i + 1]), u2h2(hv.y), a1, false);
                a2 = __builtin_amdgcn_fdot2(u2h2(wreg[4 * i + 2]), u2h2(hv.z), a2, false);
                a3 = __builtin_amdgcn_fdot2(u2h2(wreg[4 * i + 3]), u2h2(hv.w), a3, false);
            }
            float acc = (a0 + a1) + (a2 + a3);
            acc += __shfl_xor(acc, 1, 64);     // combine k-halves
            if (half == 0) dots[r] = acc + bias;
        }
        __syncthreads();

        // ---- gate math + h update for this WG's 32 dims (wave 0) ----
        if (tid < 32) {
            const float ar = dots[tid];
            const float az = dots[32 + tid];
            const float an = dots[64 + tid];
            const float rg = 1.f / (1.f + __expf(-(xr + ar)));
            const float zg = 1.f / (1.f + __expf(-(xz + az)));
            const float nn = xn + rg * an;
            const float e  = __expf(-2.f * nn);
            const float ng = (1.f - e) / (1.f + e);          // tanh
            const float hnew = (1.f - zg) * ng + zg * h_own;
            h_own = hnew;
            const int j = p * 32 + tid;
            ys[(size_t)row * HH + j] = (_Float16)hnew;
            const float other = __shfl_xor(hnew, 1, 64);
            if ((tid & 1) == 0) {
                const unsigned int pk = (unsigned int)f2h(hnew)
                                      | ((unsigned int)f2h(other) << 16);
                __hip_atomic_store(
                    hbuf + ((size_t)b * 2 + (t & 1)) * 256 + p * 16 + (tid >> 1),
                    pk, __ATOMIC_RELAXED, __HIP_MEMORY_SCOPE_AGENT);
            }
        }
        // flag store: same wave as h stores; vmcnt(0) orders them first.
        if (tid == 0) {
            __builtin_amdgcn_s_waitcnt(0);
            __hip_atomic_store(hflag + b * GPB + p, t + 1, __ATOMIC_RELAXED,
                               __HIP_MEMORY_SCOPE_AGENT);
        }
        __syncthreads();
    }
}

// ---------------------------------------------------------------------------
// 5) Fused LayerNorm + classification head. One WG per output row.
// ---------------------------------------------------------------------------
__global__ __launch_bounds__(256) void ln_head_kernel(
        const float* __restrict__ X,      // (S*B, D), row = s*16+b
        const float* __restrict__ gamma,
        const float* __restrict__ beta,
        const float* __restrict__ Wh,     // (3, 1024)
        const float* __restrict__ bh,     // (3)
        float*       __restrict__ out)    // (B*S, 3)
{
    __shared__ float red[12];
    const int r  = blockIdx.x;            // b*64 + s
    const int bI = r >> 6;
    const int s  = r & 63;
    const float* x = X + (size_t)(s * BB + bI) * DD;
    const int tid = threadIdx.x;
    const float4 v = *(const float4*)(x + tid * 4);
    float sum = v.x + v.y + v.z + v.w;
    float ss  = v.x * v.x + v.y * v.y + v.z * v.z + v.w * v.w;
#pragma unroll
    for (int o = 32; o > 0; o >>= 1) {
        sum += __shfl_down(sum, o, 64);
        ss  += __shfl_down(ss,  o, 64);
    }
    const int lane = tid & 63, w = tid >> 6;
    if (lane == 0) { red[w] = sum; red[4 + w] = ss; }
    __syncthreads();
    const float tsum = red[0] + red[1] + red[2] + red[3];
    const float tss  = red[4] + red[5] + red[6] + red[7];
    const float mu  = tsum * (1.f / (float)DD);
    const float var = tss * (1.f / (float)DD) - mu * mu;
    const float inv = rsqrtf(var + 1e-5f);
    const float4 g  = *(const float4*)(gamma + tid * 4);
    const float4 be = *(const float4*)(beta + tid * 4);
    float y0 = (v.x - mu) * inv * g.x + be.x;
    float y1 = (v.y - mu) * inv * g.y + be.y;
    float y2 = (v.z - mu) * inv * g.z + be.z;
    float y3 = (v.w - mu) * inv * g.w + be.w;
    const float4 w0 = *(const float4*)(Wh + 0 * DD + tid * 4);
    const float4 w1 = *(const float4*)(Wh + 1 * DD + tid * 4);
    const float4 w2 = *(const float4*)(Wh + 2 * DD + tid * 4);
    float p0 = y0 * w0.x + y1 * w0.y + y2 * w0.z + y3 * w0.w;
    float p1 = y0 * w1.x + y1 * w1.y + y2 * w1.z + y3 * w1.w;
    float p2 = y0 * w2.x + y1 * w2.y + y2 * w2.z + y3 * w2.w;
#pragma unroll
    for (int o = 32; o > 0; o >>= 1) {
        p0 += __shfl_down(p0, o, 64);
        p1 += __shfl_down(p1, o, 64);
        p2 += __shfl_down(p2, o, 64);
    }
    __syncthreads();
    if (lane == 0) { red[w] = p0; red[4 + w] = p1; red[8 + w] = p2; }
    __syncthreads();
    if (tid == 0) {
        out[(size_t)r * NCLS + 0] = red[0] + red[1] + red[2]  + red[3]  + bh[0];
        out[(size_t)r * NCLS + 1] = red[4] + red[5] + red[6]  + red[7]  + bh[1];
        out[(size_t)r * NCLS + 2] = red[8] + red[9] + red[10] + red[11] + bh[2];
    }
}

// ---------------------------------------------------------------------------
extern "C" void kernel_launch(void* const* d_in, const int* in_sizes, int n_in,
                              void* d_out, int out_size, void* d_ws, size_t ws_size,
                              hipStream_t stream) {
    const float* hs      = (const float*)d_in[0];
    const float* W_down  = (const float*)d_in[1];
    const float* b_down  = (const float*)d_in[2];
    const float* W_ih0   = (const float*)d_in[3];
    const float* W_hh0   = (const float*)d_in[4];
    const float* b_ih0   = (const float*)d_in[5];
    const float* b_hh0   = (const float*)d_in[6];
    const float* W_ih1   = (const float*)d_in[7];
    const float* W_hh1   = (const float*)d_in[8];
    const float* b_ih1   = (const float*)d_in[9];
    const float* b_hh1   = (const float*)d_in[10];
    const float* W_lin1  = (const float*)d_in[11];
    const float* b_lin1  = (const float*)d_in[12];
    const float* gamma   = (const float*)d_in[13];
    const float* beta    = (const float*)d_in[14];
    const float* W_head  = (const float*)d_in[15];
    const float* b_head  = (const float*)d_in[16];
    const int*   gidx    = (const int*)d_in[17];
    float* out = (float*)d_out;

    char* ws = (char*)d_ws;
    const size_t MB = (size_t)1 << 20;
    float*        pooled   = (float*)(ws);                        // 4 MB fp32
    _Float16*     pooledh  = (_Float16*)(ws + 4 * MB);            // 2 MB
    _Float16*     xd_h     = (_Float16*)(ws + 6 * MB);            // 1 MB (reused as ys0_h)
    _Float16*     xW_h     = (_Float16*)(ws + 7 * MB);            // 3 MB
    _Float16*     ys1_h    = (_Float16*)(ws + 10 * MB);           // 1 MB
    float*        xln      = (float*)(ws + 11 * MB);              // 4 MB
    unsigned int* wp0      = (unsigned int*)(ws + 15 * MB);       // 1.5 MB
    unsigned int* wp1      = (unsigned int*)(ws + 15 * MB + 1536 * 1024); // 1.5 MB
    _Float16*     wdown_h  = (_Float16*)(ws + 18 * MB);           // 1 MB
    _Float16*     wih0_h   = (_Float16*)(ws + 19 * MB);           // 1.5 MB
    _Float16*     wih1_h   = (_Float16*)(ws + 19 * MB + 1536 * 1024); // 1.5 MB
    _Float16*     wlin1_h  = (_Float16*)(ws + 22 * MB);           // 1 MB
    unsigned int* hbuf     = (unsigned int*)(ws + 23 * MB);       // 32 KB
    int*          hflag    = (int*)(ws + 23 * MB + (64 << 10));   // 2 KB
    _Float16*     ys0_h    = xd_h;                                // reuse (xd dead after ih0)

    // zero the flags (ws is poisoned before every launch)
    hipMemsetAsync(hflag, 0, 2 * BB * GPB * sizeof(int), stream);

    // 1) pooling: fp32 residual + f16 GEMM input, layout (S,B,D)
    pool_kernel<<<BB * SS, 256, 0, stream>>>(hs, gidx, pooled, pooledh);

    // 2) pack GRU recurrent weights (f16 k-pairs, k-major)
    pack_whh_kernel<<<dim3(HH / 32, H3 / 32), dim3(32, 8), 0, stream>>>(W_hh0, wp0);
    pack_whh_kernel<<<dim3(HH / 32, H3 / 32), dim3(32, 8), 0, stream>>>(W_hh1, wp1);

    // 2b) convert GEMM weights to f16
    cvt_f16_kernel<<<(HH * DD) / 2048, 256, 0, stream>>>(W_down, wdown_h, HH * DD);
    cvt_f16_kernel<<<(H3 * HH) / 2048, 256, 0, stream>>>(W_ih0, wih0_h, H3 * HH);
    cvt_f16_kernel<<<(H3 * HH) / 2048, 256, 0, stream>>>(W_ih1, wih1_h, H3 * HH);
    cvt_f16_kernel<<<(DD * HH) / 2048, 256, 0, stream>>>(W_lin1, wlin1_h, DD * HH);

    // 3) down-projection: xd = pooled @ W_down^T + b_down  (f16 out)
    gemm_mfma_kernel<true><<<dim3(HH / 64, (SS * BB) / 64), 256, 0, stream>>>(
        pooledh, wdown_h, b_down, nullptr, xd_h, SS * BB, HH, DD);

    // 4) layer-0 input projection: xW = xd @ W_ih0^T + b_ih0  (f16 out)
    gemm_mfma_kernel<true><<<dim3(H3 / 64, (SS * BB) / 64), 256, 0, stream>>>(
        xd_h, wih0_h, b_ih0, nullptr, xW_h, SS * BB, H3, HH);

    // 5) layer-0 recurrence
    gru_layer5_kernel<<<BB * GPB, 256, 0, stream>>>(
        xW_h, wp0, b_hh0, ys0_h, hbuf, hflag);

    // 6) layer-1 input projection
    gemm_mfma_kernel<true><<<dim3(H3 / 64, (SS * BB) / 64), 256, 0, stream>>>(
        ys0_h, wih1_h, b_ih1, nullptr, xW_h, SS * BB, H3, HH);

    // 7) layer-1 recurrence (fresh flag block)
    gru_layer5_kernel<<<BB * GPB, 256, 0, stream>>>(
        xW_h, wp1, b_hh1, ys1_h, hbuf, hflag + BB * GPB);

    // 8) up-projection + residual: xln = pooled + ys1 @ W_lin1^T + b_lin1 (fp32)
    gemm_mfma_kernel<false><<<dim3(DD / 64, (SS * BB) / 64), 256, 0, stream>>>(
        ys1_h, wlin1_h, b_lin1, pooled, xln, SS * BB, DD, HH);

    // 9) LayerNorm + head
    ln_head_kernel<<<BB * SS, 256, 0, stream>>>(xln, gamma, beta, W_head, b_head, out);
}